// Round 10
// baseline (652.215 us; speedup 1.0000x reference)
//
#include <hip/hip_runtime.h>
#include <hip/hip_bf16.h>

#define E_EDGES 600000
#define N_NODES 50000

typedef __attribute__((ext_vector_type(8))) short bf16x8;
typedef __attribute__((ext_vector_type(4))) short s16x4;
typedef __attribute__((ext_vector_type(4))) float f32x4;
typedef unsigned short u16;

static __device__ __forceinline__ float bf2f(u16 u) {
    unsigned int x = ((unsigned int)u) << 16;
    return __builtin_bit_cast(float, x);
}
static __device__ __forceinline__ u16 f2bf(float f) {
    return __builtin_bit_cast(u16, __float2bfloat16(f));
}
static __device__ __forceinline__ int xcd_swz(int orig, int nwg) {
    int q = nwg >> 3, r = nwg & 7;
    int x = orig & 7, o = orig >> 3;
    int base = (x < r) ? x * (q + 1) : r * (q + 1) + (x - r) * q;
    return base + o;
}

__global__ __launch_bounds__(256) void zero_kernel(f32x4* __restrict__ p, int n4) {
    int i = blockIdx.x * 256 + threadIdx.x;
    if (i < n4) p[i] = f32x4{0.f, 0.f, 0.f, 0.f};
}
__global__ __launch_bounds__(256) void zero_int_kernel(int* __restrict__ p, int n) {
    int i = blockIdx.x * 256 + threadIdx.x;
    if (i < n) p[i] = 0;
}

// ---------------- weight prep ----------------
__global__ void prep_kernel(const float* __restrict__ Wi, const float* __restrict__ Wh,
                            const float* __restrict__ Wo,
                            short* __restrict__ WiT, short* __restrict__ WhT,
                            short* __restrict__ WoT) {
    int idx = blockIdx.x * 256 + threadIdx.x;
    if (idx < 128 * 160) {
        int j = idx / 160, k = idx % 160;
        WiT[idx] = (k < 144) ? (short)f2bf(Wi[k * 128 + j]) : (short)0;
    } else if (idx < 128 * 160 + 128 * 128) {
        int t = idx - 128 * 160;
        int j = t / 128, k = t % 128;
        WhT[t] = (short)f2bf(Wh[k * 128 + j]);
    } else if (idx < 128 * 160 + 128 * 128 + 128 * 256) {
        int t = idx - 128 * 160 - 128 * 128;
        int j = t / 256, k = t % 256;
        WoT[t] = (short)f2bf(Wo[k * 128 + j]);
    }
}

// bf16 copies of x and edge_attr (rounding identical to in-kernel cvt)
__global__ __launch_bounds__(256) void prepx_kernel(const float* __restrict__ x,
                                                    const float* __restrict__ ea,
                                                    short* __restrict__ xb,
                                                    short* __restrict__ eb) {
    const int NX4 = N_NODES * 128 / 4;
    const int NE4 = E_EDGES * 16 / 4;
    int i = blockIdx.x * 256 + threadIdx.x;
    if (i < NX4) {
        f32x4 v = ((const f32x4*)x)[i];
        s16x4 o;
#pragma unroll
        for (int j = 0; j < 4; ++j) o[j] = (short)f2bf(v[j]);
        ((s16x4*)xb)[i] = o;
    } else if (i < NX4 + NE4) {
        int t = i - NX4;
        f32x4 v = ((const f32x4*)ea)[t];
        s16x4 o;
#pragma unroll
        for (int j = 0; j < 4; ++j) o[j] = (short)f2bf(v[j]);
        ((s16x4*)eb)[t] = o;
    }
}

// ---------------- CSR build ----------------
__global__ __launch_bounds__(256) void count_kernel(const int* __restrict__ ei,
                                                    int* __restrict__ deg) {
    int e = blockIdx.x * 256 + threadIdx.x;
    if (e < E_EDGES) atomicAdd(&deg[ei[E_EDGES + e]], 1);
}

__global__ __launch_bounds__(1024) void scan_kernel(const int* __restrict__ deg,
                                                    int* __restrict__ offs) {
    __shared__ int wsum[16];
    __shared__ int carry;
    const int t = threadIdx.x, lane = t & 63, wv = t >> 6;
    if (t == 0) { carry = 0; offs[0] = 0; }
    __syncthreads();
    for (int base = 0; base < N_NODES; base += 1024) {
        int i = base + t;
        int v = (i < N_NODES) ? deg[i] : 0;
        int s = v;
#pragma unroll
        for (int o = 1; o < 64; o <<= 1) {
            int u = __shfl_up(s, o, 64);
            if (lane >= o) s += u;
        }
        if (lane == 63) wsum[wv] = s;
        __syncthreads();
        if (wv == 0 && lane < 16) {
            int ws = wsum[lane];
#pragma unroll
            for (int o = 1; o < 16; o <<= 1) {
                int u = __shfl_up(ws, o, 16);
                if (lane >= o) ws += u;
            }
            wsum[lane] = ws;
        }
        __syncthreads();
        int wpre = (wv > 0) ? wsum[wv - 1] : 0;
        int incl = carry + wpre + s;
        if (i < N_NODES) offs[i + 1] = incl;
        __syncthreads();
        if (t == 1023) carry = incl;
        __syncthreads();
    }
}

__global__ __launch_bounds__(256) void scatter_kernel(const int* __restrict__ ei,
                                                      int* __restrict__ offs,
                                                      int* __restrict__ eids) {
    int e = blockIdx.x * 256 + threadIdx.x;
    if (e < E_EDGES) {
        int d = ei[E_EDGES + e];
        int p = atomicAdd(&offs[d], 1);
        eids[p] = e;
    }
}

// ---------------- segment sum via CSR (B path) ----------------
__global__ __launch_bounds__(256) void segsum_kernel(const short* __restrict__ H,
                                                     const int* __restrict__ eids,
                                                     const int* __restrict__ offs,
                                                     float* __restrict__ agg,
                                                     float* __restrict__ flg) {
    const int w = threadIdx.x >> 6, l = threadIdx.x & 63;
    const int n = blockIdx.x * 4 + w;
    if (n >= N_NODES) return;
    int b = (n == 0) ? 0 : offs[n - 1];
    int en = offs[n];
    float s0 = 0.f, s1 = 0.f, t0 = 0.f, t1 = 0.f;
    int j = b;
    for (; j + 2 <= en; j += 2) {
        int e0 = eids[j], e1 = eids[j + 1];
        unsigned int pk0 = *(const unsigned int*)(H + (size_t)e0 * 128 + l * 2);
        unsigned int pk1 = *(const unsigned int*)(H + (size_t)e1 * 128 + l * 2);
        s0 += bf2f((u16)(pk0 & 0xffffu));
        s1 += bf2f((u16)(pk0 >> 16));
        t0 += bf2f((u16)(pk1 & 0xffffu));
        t1 += bf2f((u16)(pk1 >> 16));
    }
    if (j < en) {
        int e0 = eids[j];
        unsigned int pk0 = *(const unsigned int*)(H + (size_t)e0 * 128 + l * 2);
        s0 += bf2f((u16)(pk0 & 0xffffu));
        s1 += bf2f((u16)(pk0 >> 16));
    }
    s0 += t0; s1 += t1;
    agg[(size_t)n * 128 + l * 2] = s0;
    agg[(size_t)n * 128 + l * 2 + 1] = s1;
    if (flg) {
        float s = s0 + s1;
#pragma unroll
        for (int off = 32; off; off >>= 1) s += __shfl_xor(s, off, 64);
        if (l == 0) flg[n] = s;
    }
}

__global__ __launch_bounds__(256) void flag_kernel(const float* __restrict__ agg,
                                                   float* __restrict__ flg) {
    const int w = threadIdx.x >> 6, l = threadIdx.x & 63;
    const int n = blockIdx.x * 4 + w;
    if (n >= N_NODES) return;
    const float* r = agg + (size_t)n * 128 + l * 2;
    float s = r[0] + r[1];
#pragma unroll
    for (int off = 32; off; off >>= 1) s += __shfl_xor(s, off, 64);
    if (l == 0) flg[n] = s;
}

// ---------------- A: dst-ordered H0 + fused segreduce -> agg1 (bf16 inputs) ----------------
__global__ __launch_bounds__(256) void h0dst_kernel(
    const short* __restrict__ xb, const short* __restrict__ eb,
    const short* __restrict__ WiT, const float* __restrict__ bi,
    const int* __restrict__ ei, const int* __restrict__ eids,
    const int* __restrict__ offs, short* __restrict__ H0,
    float* __restrict__ agg1) {
    __shared__ short Bx[128 * 128];  // x-part of Wi, XOR-swizzled
    __shared__ short T[64 * 128];    // swizzled output tile
    __shared__ int eloc[64], dstv[64];
    const int P = xcd_swz(blockIdx.x, gridDim.x) * 64;
    for (int i = threadIdx.x; i < 128 * 16; i += 256) {
        int row = i >> 4, cc = i & 15;
        int dstByte = row * 256 + ((cc * 16) ^ ((row & 7) << 4));
        *(bf16x8*)((char*)Bx + dstByte) = *(const bf16x8*)&WiT[row * 160 + cc * 8];
    }
    if (threadIdx.x < 64) {
        int e = eids[P + threadIdx.x];
        eloc[threadIdx.x] = e;
        dstv[threadIdx.x] = ei[E_EDGES + e];
    }
    __syncthreads();
    const int w = threadIdx.x >> 6, l = threadIdx.x & 63;
    const int c = l & 15, g = l >> 4;
    const int em = eloc[w * 16 + c];
    const int src_e = ei[em];
    const short* xr = xb + (size_t)src_e * 128;
    const short* ar = eb + (size_t)em * 16;

    bf16x8 px[4];
#pragma unroll
    for (int s = 0; s < 4; ++s) px[s] = *(const bf16x8*)(xr + s * 32 + g * 8);
    bf16x8 pe = {0, 0, 0, 0, 0, 0, 0, 0};
    if (g < 2) pe = *(const bf16x8*)(ar + g * 8);
    const int weOff = 128 + (g & 1) * 8;

    f32x4 acc[8] = {};
#pragma unroll
    for (int s = 0; s < 5; ++s) {
        const int k0 = s * 32 + g * 8;
        bf16x8 af = (s < 4) ? px[s] : pe;
#pragma unroll
        for (int nf = 0; nf < 8; ++nf) {
            const int row = nf * 16 + c;
            bf16x8 bfv;
            if (s < 4) {
                int bo = row * 256 + ((k0 * 2) ^ ((row & 7) << 4));
                bfv = *(const bf16x8*)((char*)Bx + bo);
            } else {
                bfv = *(const bf16x8*)&WiT[row * 160 + weOff];
            }
            acc[nf] = __builtin_amdgcn_mfma_f32_16x16x32_bf16(af, bfv, acc[nf], 0, 0, 0);
        }
    }
#pragma unroll
    for (int nf = 0; nf < 8; ++nf) {
        const int col = nf * 16 + c;
        const float bias = bi[col];
#pragma unroll
        for (int r = 0; r < 4; ++r) {
            const int lr2 = w * 16 + g * 4 + r;
            float v = fmaxf(acc[nf][r] + bias, 0.0f);
            int bo = lr2 * 256 + ((col * 2) ^ ((lr2 & 7) << 4));
            *(short*)((char*)T + bo) = (short)f2bf(v);
        }
    }
    __syncthreads();
#pragma unroll
    for (int it = 0; it < 4; ++it) {
        int i = threadIdx.x + it * 256;
        int lr = i >> 4, cc = i & 15;
        int bo = lr * 256 + ((cc * 16) ^ ((lr & 7) << 4));
        *(bf16x8*)&H0[(size_t)eloc[lr] * 128 + cc * 8] = *(const bf16x8*)((char*)T + bo);
    }
    // segmented reduce T -> agg1 (2 halves x 32 rows, all 256 threads)
    {
        const int h = threadIdx.x >> 7;
        const int col = threadIdx.x & 127;
        const int base = h * 32;
        const int Ph = P + base;
        int n0 = dstv[base];
        bool fh0 = (((n0 == 0) ? 0 : offs[n0 - 1]) == Ph);
        bool fh1 = (offs[dstv[base + 31]] == Ph + 32);
        float sum = 0.f;
        int cur = n0, segStart = base;
        for (int lr = base; lr < base + 32; ++lr) {
            int d = dstv[lr];
            int bo = lr * 256 + ((col * 2) ^ ((lr & 7) << 4));
            float v = bf2f(*(const u16*)((char*)T + bo));
            if (d != cur) {
                bool comp = (segStart > base) || fh0;
                float* dp = agg1 + (size_t)cur * 128 + col;
                if (comp) *dp = sum; else atomicAdd(dp, sum);
                cur = d; segStart = lr; sum = v;
            } else {
                sum += v;
            }
        }
        bool comp = ((segStart > base) || fh0) && fh1;
        float* dp = agg1 + (size_t)cur * 128 + col;
        if (comp) *dp = sum; else atomicAdd(dp, sum);
    }
}

// ---------------- A: dst-ordered iteration ----------------
__global__ __launch_bounds__(256) void iter_dst_kernel(
    const float* __restrict__ agg1, const short* __restrict__ H0,
    const short* __restrict__ WhT, const float* __restrict__ bh,
    const int* __restrict__ ei, const int* __restrict__ rev,
    const int* __restrict__ eids, const int* __restrict__ offs,
    float* __restrict__ agg2) {
    __shared__ short B[128 * 136];
    __shared__ short T[64 * 136];
    __shared__ int eloc[64], dstv[64];
    const int P = xcd_swz(blockIdx.x, gridDim.x) * 64;
    for (int i = threadIdx.x; i < 128 * 16; i += 256) {
        int row = i >> 4, cc = i & 15;
        *(bf16x8*)&B[row * 136 + cc * 8] = *(const bf16x8*)&WhT[row * 128 + cc * 8];
    }
    if (threadIdx.x < 64) {
        int e = eids[P + threadIdx.x];
        eloc[threadIdx.x] = e;
        dstv[threadIdx.x] = ei[E_EDGES + e];
    }
    __syncthreads();
    const int w = threadIdx.x >> 6, l = threadIdx.x & 63;
    const int c = l & 15, g = l >> 4;
    const int e_m = eloc[w * 16 + c];
    const int src_e = ei[e_m];
    const int rev_e = rev[e_m];
    const float* arow = agg1 + (size_t)src_e * 128;
    const short* hrow = H0 + (size_t)rev_e * 128;

    bf16x8 stg[4];
#pragma unroll
    for (int it = 0; it < 4; ++it) {
        int i = threadIdx.x + it * 256;
        int lr = i >> 4, cc = i & 15;
        stg[it] = *(const bf16x8*)&H0[(size_t)eloc[lr] * 128 + cc * 8];
    }
    f32x4 pa[4][2];
    bf16x8 ph[4];
#pragma unroll
    for (int s = 0; s < 4; ++s) {
        pa[s][0] = *(const f32x4*)(arow + s * 32 + g * 8);
        pa[s][1] = *(const f32x4*)(arow + s * 32 + g * 8 + 4);
        ph[s] = *(const bf16x8*)(hrow + s * 32 + g * 8);
    }
#pragma unroll
    for (int it = 0; it < 4; ++it) {
        int i = threadIdx.x + it * 256;
        int lr = i >> 4, cc = i & 15;
        *(bf16x8*)&T[lr * 136 + cc * 8] = stg[it];
    }
    __syncthreads();

    f32x4 acc[8] = {};
#pragma unroll
    for (int s = 0; s < 4; ++s) {
        const int k0 = s * 32 + g * 8;
        bf16x8 af;
#pragma unroll
        for (int j = 0; j < 8; ++j) {
            float aj = ((j < 4) ? pa[s][0][j] : pa[s][1][j - 4]) - bf2f((u16)ph[s][j]);
            af[j] = (short)f2bf(aj);
        }
#pragma unroll
        for (int nf = 0; nf < 8; ++nf) {
            bf16x8 bfv = *(const bf16x8*)&B[(nf * 16 + c) * 136 + k0];
            acc[nf] = __builtin_amdgcn_mfma_f32_16x16x32_bf16(af, bfv, acc[nf], 0, 0, 0);
        }
    }
#pragma unroll
    for (int nf = 0; nf < 8; ++nf) {
        const int col = nf * 16 + c;
        const float bias = bh[col];
#pragma unroll
        for (int r = 0; r < 4; ++r) {
            const int lr2 = w * 16 + g * 4 + r;
            float res = bf2f((u16)T[lr2 * 136 + col]);
            float v = fmaxf(acc[nf][r] + bias + res, 0.0f);
            T[lr2 * 136 + col] = (short)f2bf(v);
        }
    }
    __syncthreads();
    {
        const int h = threadIdx.x >> 7;
        const int col = threadIdx.x & 127;
        const int base = h * 32;
        const int Ph = P + base;
        int n0 = dstv[base];
        bool fh0 = (((n0 == 0) ? 0 : offs[n0 - 1]) == Ph);
        bool fh1 = (offs[dstv[base + 31]] == Ph + 32);
        float sum = 0.f;
        int cur = n0, segStart = base;
        for (int lr = base; lr < base + 32; ++lr) {
            int d = dstv[lr];
            float v = bf2f((u16)T[lr * 136 + col]);
            if (d != cur) {
                bool comp = (segStart > base) || fh0;
                float* dp = agg2 + (size_t)cur * 128 + col;
                if (comp) *dp = sum; else atomicAdd(dp, sum);
                cur = d; segStart = lr; sum = v;
            } else {
                sum += v;
            }
        }
        bool comp = ((segStart > base) || fh0) && fh1;
        float* dp = agg2 + (size_t)cur * 128 + col;
        if (comp) *dp = sum; else atomicAdd(dp, sum);
    }
}

// ---------------- A: fused final iteration (residual hoisted) ----------------
__global__ __launch_bounds__(256) void iter2F_kernel(
    const float* __restrict__ agg1, const float* __restrict__ agg2,
    const short* __restrict__ H0, const short* __restrict__ WhT,
    const float* __restrict__ bh, const int* __restrict__ ei,
    const int* __restrict__ rev, const int* __restrict__ eids,
    const int* __restrict__ offs, float* __restrict__ aggF) {
    __shared__ short B[128 * 128];   // Wh, XOR-swizzled
    __shared__ short TR[64 * 128];   // swizzled: H0[rev] -> H1[rev] -> H2
    __shared__ int eloc[64], dstv[64], revl[64];
    const int P = xcd_swz(blockIdx.x, gridDim.x) * 64;
    for (int i = threadIdx.x; i < 128 * 16; i += 256) {
        int row = i >> 4, cc = i & 15;
        int dstByte = row * 256 + ((cc * 16) ^ ((row & 7) << 4));
        *(bf16x8*)((char*)B + dstByte) = *(const bf16x8*)&WhT[row * 128 + cc * 8];
    }
    if (threadIdx.x < 64) {
        int e = eids[P + threadIdx.x];
        eloc[threadIdx.x] = e;
        dstv[threadIdx.x] = ei[E_EDGES + e];
        revl[threadIdx.x] = rev[e];
    }
    __syncthreads();
#pragma unroll
    for (int it = 0; it < 4; ++it) {
        int i = threadIdx.x + it * 256;
        int lr = i >> 4, cc = i & 15;
        int bo = lr * 256 + ((cc * 16) ^ ((lr & 7) << 4));
        *(bf16x8*)((char*)TR + bo) = *(const bf16x8*)&H0[(size_t)revl[lr] * 128 + cc * 8];
    }
    const int w = threadIdx.x >> 6, l = threadIdx.x & 63;
    const int c = l & 15, g = l >> 4;
    const int rl = w * 16 + c;
    const int em = eloc[rl];
    const int dst_em = dstv[rl];
    const int src_m = ei[em];
    const short* h0row = H0 + (size_t)em * 128;
    const float* a1row = agg1 + (size_t)dst_em * 128;
    const float* a2row = agg2 + (size_t)src_m * 128;

    bf16x8 ph[4];
    f32x4 pa1[4][2], pa2[4][2];
#pragma unroll
    for (int s = 0; s < 4; ++s) {
        ph[s] = *(const bf16x8*)(h0row + s * 32 + g * 8);
        pa1[s][0] = *(const f32x4*)(a1row + s * 32 + g * 8);
        pa1[s][1] = *(const f32x4*)(a1row + s * 32 + g * 8 + 4);
        pa2[s][0] = *(const f32x4*)(a2row + s * 32 + g * 8);
        pa2[s][1] = *(const f32x4*)(a2row + s * 32 + g * 8 + 4);
    }
    // hoisted C-layout residual reads: same rows as the block's ph stream -> L2-hot
    u16 resb[8][4];
#pragma unroll
    for (int nf = 0; nf < 8; ++nf)
#pragma unroll
        for (int r = 0; r < 4; ++r) {
            const int lr2 = w * 16 + g * 4 + r;
            resb[nf][r] = (u16)H0[(size_t)eloc[lr2] * 128 + nf * 16 + c];
        }
    __syncthreads();

    // phase 1: H1[rev_em] = relu(H0[rev_em] + (agg1[dst_em] - H0[em]) @ Wh + bh)
    f32x4 acc[8] = {};
#pragma unroll
    for (int s = 0; s < 4; ++s) {
        const int k0 = s * 32 + g * 8;
        bf16x8 af;
#pragma unroll
        for (int j = 0; j < 8; ++j) {
            float aj = ((j < 4) ? pa1[s][0][j] : pa1[s][1][j - 4]) - bf2f((u16)ph[s][j]);
            af[j] = (short)f2bf(aj);
        }
#pragma unroll
        for (int nf = 0; nf < 8; ++nf) {
            const int row = nf * 16 + c;
            int bo = row * 256 + ((k0 * 2) ^ ((row & 7) << 4));
            bf16x8 bfv = *(const bf16x8*)((char*)B + bo);
            acc[nf] = __builtin_amdgcn_mfma_f32_16x16x32_bf16(af, bfv, acc[nf], 0, 0, 0);
        }
    }
#pragma unroll
    for (int nf = 0; nf < 8; ++nf) {
        const int col = nf * 16 + c;
        const float bias = bh[col];
#pragma unroll
        for (int r = 0; r < 4; ++r) {
            const int lr2 = w * 16 + g * 4 + r;
            int bo = lr2 * 256 + ((col * 2) ^ ((lr2 & 7) << 4));
            float res = bf2f(*(const u16*)((char*)TR + bo));
            float v = fmaxf(acc[nf][r] + bias + res, 0.0f);
            *(short*)((char*)TR + bo) = (short)f2bf(v);
        }
    }
    __syncthreads();
    // phase 2: H2[em] = relu(H0[em] + (agg2[src_em] - H1[rev_em]) @ Wh + bh)
    f32x4 acc2[8] = {};
#pragma unroll
    for (int s = 0; s < 4; ++s) {
        const int k0 = s * 32 + g * 8;
        int boT = rl * 256 + ((k0 * 2) ^ ((rl & 7) << 4));
        bf16x8 hv = *(const bf16x8*)((char*)TR + boT);
        bf16x8 af;
#pragma unroll
        for (int j = 0; j < 8; ++j) {
            float aj = ((j < 4) ? pa2[s][0][j] : pa2[s][1][j - 4]) - bf2f((u16)hv[j]);
            af[j] = (short)f2bf(aj);
        }
#pragma unroll
        for (int nf = 0; nf < 8; ++nf) {
            const int row = nf * 16 + c;
            int bo = row * 256 + ((k0 * 2) ^ ((row & 7) << 4));
            bf16x8 bfv = *(const bf16x8*)((char*)B + bo);
            acc2[nf] = __builtin_amdgcn_mfma_f32_16x16x32_bf16(af, bfv, acc2[nf], 0, 0, 0);
        }
    }
    __syncthreads();  // all H1 reads complete before overwriting TR with H2
#pragma unroll
    for (int nf = 0; nf < 8; ++nf) {
        const int col = nf * 16 + c;
        const float bias = bh[col];
#pragma unroll
        for (int r = 0; r < 4; ++r) {
            const int lr2 = w * 16 + g * 4 + r;
            float v = fmaxf(acc2[nf][r] + bias + bf2f(resb[nf][r]), 0.0f);
            int bo = lr2 * 256 + ((col * 2) ^ ((lr2 & 7) << 4));
            *(short*)((char*)TR + bo) = (short)f2bf(v);
        }
    }
    __syncthreads();
    {
        const int h = threadIdx.x >> 7;
        const int col = threadIdx.x & 127;
        const int base = h * 32;
        const int Ph = P + base;
        int n0 = dstv[base];
        bool fh0 = (((n0 == 0) ? 0 : offs[n0 - 1]) == Ph);
        bool fh1 = (offs[dstv[base + 31]] == Ph + 32);
        float sum = 0.f;
        int cur = n0, segStart = base;
        for (int lr = base; lr < base + 32; ++lr) {
            int d = dstv[lr];
            int bo = lr * 256 + ((col * 2) ^ ((lr & 7) << 4));
            float v = bf2f(*(const u16*)((char*)TR + bo));
            if (d != cur) {
                bool comp = (segStart > base) || fh0;
                float* dp = aggF + (size_t)cur * 128 + col;
                if (comp) *dp = sum; else atomicAdd(dp, sum);
                cur = d; segStart = lr; sum = v;
            } else {
                sum += v;
            }
        }
        bool comp = ((segStart > base) || fh0) && fh1;
        float* dp = aggF + (size_t)cur * 128 + col;
        if (comp) *dp = sum; else atomicAdd(dp, sum);
    }
}

// ---------------- B-path kernels (unchanged) ----------------
__global__ __launch_bounds__(256) void h0s_kernel(
    const float* __restrict__ x, const float* __restrict__ eattr,
    const short* __restrict__ WiT, const float* __restrict__ bi,
    const int* __restrict__ ei, short* __restrict__ H0) {
    __shared__ short B[128 * 168];
    for (int i = threadIdx.x; i < 128 * 20; i += 256) {
        int row = i / 20, cc = i % 20;
        *(bf16x8*)&B[row * 168 + cc * 8] = *(const bf16x8*)&WiT[row * 160 + cc * 8];
    }
    __syncthreads();
    const int w = threadIdx.x >> 6, l = threadIdx.x & 63;
    const int c = l & 15, g = l >> 4;
    const int e0 = blockIdx.x * 64 + w * 16;
    const int em = e0 + c;
    const int src_e = ei[em];
    const float* xr = x + (size_t)src_e * 128;
    const float* ar = eattr + (size_t)em * 16;

    f32x4 acc[8] = {};
#pragma unroll
    for (int s = 0; s < 5; ++s) {
        const int k0 = s * 32 + g * 8;
        float av[8];
        if (s < 4) {
            f32x4 p0 = *(const f32x4*)(xr + k0);
            f32x4 p1 = *(const f32x4*)(xr + k0 + 4);
#pragma unroll
            for (int j = 0; j < 4; ++j) { av[j] = p0[j]; av[j + 4] = p1[j]; }
        } else {
            if (g < 2) {
                f32x4 p0 = *(const f32x4*)(ar + g * 8);
                f32x4 p1 = *(const f32x4*)(ar + g * 8 + 4);
#pragma unroll
                for (int j = 0; j < 4; ++j) { av[j] = p0[j]; av[j + 4] = p1[j]; }
            } else {
#pragma unroll
                for (int j = 0; j < 8; ++j) av[j] = 0.f;
            }
        }
        bf16x8 af;
#pragma unroll
        for (int j = 0; j < 8; ++j) af[j] = (short)f2bf(av[j]);
#pragma unroll
        for (int nf = 0; nf < 8; ++nf) {
            bf16x8 bfv = *(const bf16x8*)&B[(nf * 16 + c) * 168 + k0];
            acc[nf] = __builtin_amdgcn_mfma_f32_16x16x32_bf16(af, bfv, acc[nf], 0, 0, 0);
        }
    }
#pragma unroll
    for (int nf = 0; nf < 8; ++nf) {
        const int col = nf * 16 + c;
        const float bias = bi[col];
#pragma unroll
        for (int r = 0; r < 4; ++r) {
            const int er = e0 + g * 4 + r;
            float v = fmaxf(acc[nf][r] + bias, 0.0f);
            H0[(size_t)er * 128 + col] = (short)f2bf(v);
        }
    }
}

__global__ __launch_bounds__(256) void iterx_kernel(
    const float* __restrict__ agg, const short* __restrict__ Hrev,
    const short* Hres, const short* __restrict__ WhT,
    const float* __restrict__ bh, const int* __restrict__ ei,
    const int* __restrict__ rev, short* Hout) {
    __shared__ short B[128 * 136];
    for (int i = threadIdx.x; i < 128 * 16; i += 256) {
        int row = i >> 4, cc = i & 15;
        *(bf16x8*)&B[row * 136 + cc * 8] = *(const bf16x8*)&WhT[row * 128 + cc * 8];
    }
    __syncthreads();
    const int w = threadIdx.x >> 6, l = threadIdx.x & 63;
    const int c = l & 15, g = l >> 4;
    const int e0 = blockIdx.x * 64 + w * 16;
    const int em = e0 + c;
    const int src_e = ei[em];
    const int rev_e = rev[em];
    const float* arow = agg + (size_t)src_e * 128;
    const short* hrow = Hrev + (size_t)rev_e * 128;

    f32x4 acc[8] = {};
#pragma unroll
    for (int s = 0; s < 4; ++s) {
        const int k0 = s * 32 + g * 8;
        f32x4 p0 = *(const f32x4*)(arow + k0);
        f32x4 p1 = *(const f32x4*)(arow + k0 + 4);
        bf16x8 hv = *(const bf16x8*)(hrow + k0);
        bf16x8 af;
#pragma unroll
        for (int j = 0; j < 8; ++j) {
            float aj = ((j < 4) ? p0[j] : p1[j - 4]) - bf2f((u16)hv[j]);
            af[j] = (short)f2bf(aj);
        }
#pragma unroll
        for (int nf = 0; nf < 8; ++nf) {
            bf16x8 bfv = *(const bf16x8*)&B[(nf * 16 + c) * 136 + k0];
            acc[nf] = __builtin_amdgcn_mfma_f32_16x16x32_bf16(af, bfv, acc[nf], 0, 0, 0);
        }
    }
#pragma unroll
    for (int nf = 0; nf < 8; ++nf) {
        const int col = nf * 16 + c;
        const float bias = bh[col];
#pragma unroll
        for (int r = 0; r < 4; ++r) {
            const int er = e0 + g * 4 + r;
            float v = acc[nf][r] + bias + bf2f((u16)Hres[(size_t)er * 128 + col]);
            v = fmaxf(v, 0.0f);
            Hout[(size_t)er * 128 + col] = (short)f2bf(v);
        }
    }
}

// ---------------- LOW-fallback kernels ----------------
__global__ __launch_bounds__(256) void h0_kernel(
    const float* __restrict__ x, const float* __restrict__ eattr,
    const short* __restrict__ WiT, const float* __restrict__ bi,
    const int* __restrict__ ei, short* __restrict__ H0, float* __restrict__ agg) {
    __shared__ short B[128 * 168];
    for (int i = threadIdx.x; i < 128 * 20; i += 256) {
        int row = i / 20, cc = i % 20;
        *(bf16x8*)&B[row * 168 + cc * 8] = *(const bf16x8*)&WiT[row * 160 + cc * 8];
    }
    __syncthreads();
    const int w = threadIdx.x >> 6, l = threadIdx.x & 63;
    const int c = l & 15, g = l >> 4;
    const int e0 = blockIdx.x * 64 + w * 16;
    const int em = e0 + c;
    const int src_e = ei[em];
    const float* xr = x + (size_t)src_e * 128;
    const float* ar = eattr + (size_t)em * 16;
    f32x4 acc[8] = {};
#pragma unroll
    for (int s = 0; s < 5; ++s) {
        const int k0 = s * 32 + g * 8;
        float av[8];
        if (s < 4) {
            f32x4 p0 = *(const f32x4*)(xr + k0);
            f32x4 p1 = *(const f32x4*)(xr + k0 + 4);
#pragma unroll
            for (int j = 0; j < 4; ++j) { av[j] = p0[j]; av[j + 4] = p1[j]; }
        } else {
            if (g < 2) {
                f32x4 p0 = *(const f32x4*)(ar + g * 8);
                f32x4 p1 = *(const f32x4*)(ar + g * 8 + 4);
#pragma unroll
                for (int j = 0; j < 4; ++j) { av[j] = p0[j]; av[j + 4] = p1[j]; }
            } else {
#pragma unroll
                for (int j = 0; j < 8; ++j) av[j] = 0.f;
            }
        }
        bf16x8 af;
#pragma unroll
        for (int j = 0; j < 8; ++j) af[j] = (short)f2bf(av[j]);
#pragma unroll
        for (int nf = 0; nf < 8; ++nf) {
            bf16x8 bfv = *(const bf16x8*)&B[(nf * 16 + c) * 168 + k0];
            acc[nf] = __builtin_amdgcn_mfma_f32_16x16x32_bf16(af, bfv, acc[nf], 0, 0, 0);
        }
    }
    int dsts[4];
#pragma unroll
    for (int r = 0; r < 4; ++r) dsts[r] = ei[E_EDGES + e0 + g * 4 + r];
#pragma unroll
    for (int nf = 0; nf < 8; ++nf) {
        const int col = nf * 16 + c;
        const float bias = bi[col];
#pragma unroll
        for (int r = 0; r < 4; ++r) {
            const int er = e0 + g * 4 + r;
            float v = fmaxf(acc[nf][r] + bias, 0.0f);
            u16 hb = f2bf(v);
            H0[(size_t)er * 128 + col] = (short)hb;
            atomicAdd(agg + (size_t)dsts[r] * 128 + col, bf2f(hb));
        }
    }
}

__global__ __launch_bounds__(256) void iter_atomic_kernel(
    const float* __restrict__ aggin, const short* __restrict__ Hin,
    const short* __restrict__ H0, const short* __restrict__ WhT,
    const float* __restrict__ bh, const int* __restrict__ ei,
    const int* __restrict__ rev, float* __restrict__ aggout) {
    __shared__ short B[128 * 136];
    for (int i = threadIdx.x; i < 128 * 16; i += 256) {
        int row = i >> 4, cc = i & 15;
        *(bf16x8*)&B[row * 136 + cc * 8] = *(const bf16x8*)&WhT[row * 128 + cc * 8];
    }
    __syncthreads();
    const int w = threadIdx.x >> 6, l = threadIdx.x & 63;
    const int c = l & 15, g = l >> 4;
    const int e0 = blockIdx.x * 64 + w * 16;
    const int em = e0 + c;
    const int src_e = ei[em];
    const int rev_e = rev[em];
    const float* arow = aggin + (size_t)src_e * 128;
    const short* hrow = Hin + (size_t)rev_e * 128;

    f32x4 acc[8] = {};
#pragma unroll
    for (int s = 0; s < 4; ++s) {
        const int k0 = s * 32 + g * 8;
        f32x4 p0 = *(const f32x4*)(arow + k0);
        f32x4 p1 = *(const f32x4*)(arow + k0 + 4);
        bf16x8 hv = *(const bf16x8*)(hrow + k0);
        bf16x8 af;
#pragma unroll
        for (int j = 0; j < 8; ++j) {
            float aj = ((j < 4) ? p0[j] : p1[j - 4]) - bf2f((u16)hv[j]);
            af[j] = (short)f2bf(aj);
        }
#pragma unroll
        for (int nf = 0; nf < 8; ++nf) {
            bf16x8 bfv = *(const bf16x8*)&B[(nf * 16 + c) * 136 + k0];
            acc[nf] = __builtin_amdgcn_mfma_f32_16x16x32_bf16(af, bfv, acc[nf], 0, 0, 0);
        }
    }
    int dsts[4];
#pragma unroll
    for (int r = 0; r < 4; ++r) dsts[r] = ei[E_EDGES + e0 + g * 4 + r];
#pragma unroll
    for (int nf = 0; nf < 8; ++nf) {
        const int col = nf * 16 + c;
        const float bias = bh[col];
#pragma unroll
        for (int r = 0; r < 4; ++r) {
            const int er = e0 + g * 4 + r;
            float v = acc[nf][r] + bias + bf2f((u16)H0[(size_t)er * 128 + col]);
            v = fmaxf(v, 0.0f);
            atomicAdd(aggout + (size_t)dsts[r] * 128 + col, bf2f(f2bf(v)));
        }
    }
}

__global__ __launch_bounds__(256) void iter2c_kernel(
    const float* __restrict__ agg1, const float* __restrict__ agg2,
    const short* __restrict__ H0, const short* __restrict__ WhT,
    const float* __restrict__ bh, const int* __restrict__ ei,
    const int* __restrict__ rev, float* __restrict__ aggF) {
    __shared__ short B[128 * 136];
    __shared__ short T[4][16 * 136];
    for (int i = threadIdx.x; i < 128 * 16; i += 256) {
        int row = i >> 4, cc = i & 15;
        *(bf16x8*)&B[row * 136 + cc * 8] = *(const bf16x8*)&WhT[row * 128 + cc * 8];
    }
    __syncthreads();
    const int w = threadIdx.x >> 6, l = threadIdx.x & 63;
    const int c = l & 15, g = l >> 4;
    const int e0 = blockIdx.x * 64 + w * 16;
    const int em = e0 + c;
    const int dst_em = ei[E_EDGES + em];
    const int src_em = ei[em];
    const float* a1row = agg1 + (size_t)dst_em * 128;
    const float* a2row = agg2 + (size_t)src_em * 128;
    const short* h0row = H0 + (size_t)em * 128;
    int rows[4], revs[4], dsts[4];
#pragma unroll
    for (int r = 0; r < 4; ++r) {
        rows[r] = e0 + g * 4 + r;
        revs[r] = rev[rows[r]];
        dsts[r] = ei[E_EDGES + rows[r]];
    }
    f32x4 acc[8] = {};
#pragma unroll
    for (int s = 0; s < 4; ++s) {
        const int k0 = s * 32 + g * 8;
        f32x4 p0 = *(const f32x4*)(a1row + k0);
        f32x4 p1 = *(const f32x4*)(a1row + k0 + 4);
        bf16x8 hv = *(const bf16x8*)(h0row + k0);
        bf16x8 af;
#pragma unroll
        for (int j = 0; j < 8; ++j) {
            float aj = ((j < 4) ? p0[j] : p1[j - 4]) - bf2f((u16)hv[j]);
            af[j] = (short)f2bf(aj);
        }
#pragma unroll
        for (int nf = 0; nf < 8; ++nf) {
            bf16x8 bfv = *(const bf16x8*)&B[(nf * 16 + c) * 136 + k0];
            acc[nf] = __builtin_amdgcn_mfma_f32_16x16x32_bf16(af, bfv, acc[nf], 0, 0, 0);
        }
    }
#pragma unroll
    for (int nf = 0; nf < 8; ++nf) {
        const int col = nf * 16 + c;
        const float bias = bh[col];
#pragma unroll
        for (int r = 0; r < 4; ++r) {
            float res = bf2f((u16)H0[(size_t)revs[r] * 128 + col]);
            float v = fmaxf(acc[nf][r] + bias + res, 0.0f);
            T[w][(g * 4 + r) * 136 + col] = (short)f2bf(v);
        }
    }
    __syncthreads();
    f32x4 acc2[8] = {};
#pragma unroll
    for (int s = 0; s < 4; ++s) {
        const int k0 = s * 32 + g * 8;
        f32x4 p0 = *(const f32x4*)(a2row + k0);
        f32x4 p1 = *(const f32x4*)(a2row + k0 + 4);
        bf16x8 hv = *(const bf16x8*)&T[w][c * 136 + k0];
        bf16x8 af;
#pragma unroll
        for (int j = 0; j < 8; ++j) {
            float aj = ((j < 4) ? p0[j] : p1[j - 4]) - bf2f((u16)hv[j]);
            af[j] = (short)f2bf(aj);
        }
#pragma unroll
        for (int nf = 0; nf < 8; ++nf) {
            bf16x8 bfv = *(const bf16x8*)&B[(nf * 16 + c) * 136 + k0];
            acc2[nf] = __builtin_amdgcn_mfma_f32_16x16x32_bf16(af, bfv, acc2[nf], 0, 0, 0);
        }
    }
#pragma unroll
    for (int nf = 0; nf < 8; ++nf) {
        const int col = nf * 16 + c;
        const float bias = bh[col];
#pragma unroll
        for (int r = 0; r < 4; ++r) {
            float res = bf2f((u16)H0[(size_t)rows[r] * 128 + col]);
            float v = fmaxf(acc2[nf][r] + bias + res, 0.0f);
            atomicAdd(aggF + (size_t)dsts[r] * 128 + col, v);
        }
    }
}

// ---------------- output ----------------
__global__ __launch_bounds__(256) void out_kernel(
    const float* __restrict__ x, const float* agg,
    const float* __restrict__ flg, const short* __restrict__ WoT,
    const float* __restrict__ bo, float* out) {
    __shared__ short B[128 * 256];
    for (int i = threadIdx.x; i < 128 * 32; i += 256) {
        int row = i >> 5, cc = i & 31;
        int dstByte = row * 512 + ((cc * 16) ^ ((row & 7) << 4));
        *(bf16x8*)((char*)B + dstByte) = *(const bf16x8*)&WoT[row * 256 + cc * 8];
    }
    __syncthreads();
    const int w = threadIdx.x >> 6, l = threadIdx.x & 63;
    const int c = l & 15, g = l >> 4;
    const int n0 = blockIdx.x * 64 + w * 16;
    const int nm = n0 + c;
    const int nmc = nm < N_NODES ? nm : N_NODES - 1;
    const float* xr = x + (size_t)nmc * 128;
    const float* mr = agg + (size_t)nmc * 128;
    const bool usex = (flg[nmc] == 0.0f);
    f32x4 acc[8] = {};
#pragma unroll
    for (int s = 0; s < 8; ++s) {
        const int k0 = s * 32 + g * 8;
        const float* srcp;
        int kk;
        if (s < 4) { srcp = xr; kk = k0; }
        else       { srcp = usex ? xr : mr; kk = k0 - 128; }
        f32x4 p0 = *(const f32x4*)(srcp + kk);
        f32x4 p1 = *(const f32x4*)(srcp + kk + 4);
        bf16x8 af;
#pragma unroll
        for (int j = 0; j < 4; ++j) {
            af[j] = (short)f2bf(p0[j]);
            af[j + 4] = (short)f2bf(p1[j]);
        }
#pragma unroll
        for (int nf = 0; nf < 8; ++nf) {
            int row = nf * 16 + c;
            int byteOff = row * 512 + ((k0 * 2) ^ ((row & 7) << 4));
            bf16x8 bfv = *(const bf16x8*)((char*)B + byteOff);
            acc[nf] = __builtin_amdgcn_mfma_f32_16x16x32_bf16(af, bfv, acc[nf], 0, 0, 0);
        }
    }
#pragma unroll
    for (int nf = 0; nf < 8; ++nf) {
        const int col = nf * 16 + c;
        const float bias = bo[col];
#pragma unroll
        for (int r = 0; r < 4; ++r) {
            const int er = n0 + g * 4 + r;
            if (er < N_NODES) {
                float v = fmaxf(acc[nf][r] + bias, 0.0f);
                out[(size_t)er * 128 + col] = v;
            }
        }
    }
}

extern "C" void kernel_launch(void* const* d_in, const int* in_sizes, int n_in,
                              void* d_out, int out_size, void* d_ws, size_t ws_size,
                              hipStream_t stream) {
    const float* x     = (const float*)d_in[0];
    const float* eattr = (const float*)d_in[1];
    const float* Wi    = (const float*)d_in[2];
    const float* bi    = (const float*)d_in[3];
    const float* Wh    = (const float*)d_in[4];
    const float* bh    = (const float*)d_in[5];
    const float* Wo    = (const float*)d_in[6];
    const float* bo    = (const float*)d_in[7];
    const int*   ei    = (const int*)d_in[8];
    const int*   rev   = (const int*)d_in[9];
    float* out = (float*)d_out;
    (void)in_sizes; (void)n_in; (void)out_size;

    char* ws = (char*)d_ws;
    size_t off = 0;
    auto alloc = [&](size_t bytes) {
        void* p = ws + off;
        off = (off + bytes + 255) & ~(size_t)255;
        return p;
    };
    const int AGG4 = N_NODES * 128 / 4;
    const int EG = E_EDGES / 64;           // 9375
    const int EB = (E_EDGES + 255) / 256;  // 2344
    const int NB4 = (N_NODES + 3) / 4;     // 12500
    const int PREPG = (128 * 160 + 128 * 128 + 128 * 256 + 255) / 256;
    const int PREPXG = (N_NODES * 128 / 4 + E_EDGES * 16 / 4 + 255) / 256;

    if (ws_size >= (size_t)337 * 1000 * 1000) {
        // ---- Option B: fully streaming ----
        short* H0  = (short*)alloc((size_t)E_EDGES * 128 * 2);
        short* H1  = (short*)alloc((size_t)E_EDGES * 128 * 2);
        float* agg = (float*)alloc((size_t)N_NODES * 128 * 4);
        float* flg = (float*)alloc((size_t)N_NODES * 4);
        short* WiT = (short*)alloc(128 * 160 * 2);
        short* WhT = (short*)alloc(128 * 128 * 2);
        short* WoT = (short*)alloc(128 * 256 * 2);
        int* deg   = (int*)alloc((size_t)N_NODES * 4);
        int* offs  = (int*)alloc((size_t)(N_NODES + 1) * 4);
        int* eids  = (int*)alloc((size_t)E_EDGES * 4);

        zero_int_kernel<<<(N_NODES + 255) / 256, 256, 0, stream>>>(deg, N_NODES);
        prep_kernel<<<PREPG, 256, 0, stream>>>(Wi, Wh, Wo, WiT, WhT, WoT);
        count_kernel<<<EB, 256, 0, stream>>>(ei, deg);
        scan_kernel<<<1, 1024, 0, stream>>>(deg, offs);
        scatter_kernel<<<EB, 256, 0, stream>>>(ei, offs, eids);
        h0s_kernel<<<EG, 256, 0, stream>>>(x, eattr, WiT, bi, ei, H0);
        segsum_kernel<<<NB4, 256, 0, stream>>>(H0, eids, offs, agg, nullptr);
        iterx_kernel<<<EG, 256, 0, stream>>>(agg, H0, H0, WhT, bh, ei, rev, H1);
        segsum_kernel<<<NB4, 256, 0, stream>>>(H1, eids, offs, agg, nullptr);
        iterx_kernel<<<EG, 256, 0, stream>>>(agg, H1, H0, WhT, bh, ei, rev, H0);
        segsum_kernel<<<NB4, 256, 0, stream>>>(H0, eids, offs, out, flg);
        out_kernel<<<(N_NODES + 63) / 64, 256, 0, stream>>>(x, out, flg, WoT, bo, out);
    } else if (ws_size >= (size_t)210 * 1000 * 1000) {
        // ---- Option A (r10): bf16 x/eattr (aliased into agg2/out), residual hoist ----
        short* H0   = (short*)alloc((size_t)E_EDGES * 128 * 2);
        float* agg1 = (float*)alloc((size_t)N_NODES * 128 * 4);
        float* agg2 = (float*)alloc((size_t)N_NODES * 128 * 4);
        float* flg  = (float*)alloc((size_t)N_NODES * 4);
        short* WiT  = (short*)alloc(128 * 160 * 2);
        short* WhT  = (short*)alloc(128 * 128 * 2);
        short* WoT  = (short*)alloc(128 * 256 * 2);
        int* deg    = (int*)alloc((size_t)N_NODES * 4);
        int* offs   = (int*)alloc((size_t)(N_NODES + 1) * 4);
        int* eids   = (int*)alloc((size_t)E_EDGES * 4);
        // xb aliases agg2 (dead until after h0dst); eb aliases out (zeroed after h0dst)
        short* xbuf = (short*)agg2;   // 12.8 MB of 25.6 MB
        short* ebuf = (short*)out;    // 19.2 MB of 25.6 MB

        zero_int_kernel<<<(N_NODES + 255) / 256, 256, 0, stream>>>(deg, N_NODES);
        zero_kernel<<<(AGG4 + 255) / 256, 256, 0, stream>>>((f32x4*)agg1, AGG4);
        prep_kernel<<<PREPG, 256, 0, stream>>>(Wi, Wh, Wo, WiT, WhT, WoT);
        prepx_kernel<<<PREPXG, 256, 0, stream>>>(x, eattr, xbuf, ebuf);
        count_kernel<<<EB, 256, 0, stream>>>(ei, deg);
        scan_kernel<<<1, 1024, 0, stream>>>(deg, offs);
        scatter_kernel<<<EB, 256, 0, stream>>>(ei, offs, eids);
        h0dst_kernel<<<EG, 256, 0, stream>>>(xbuf, ebuf, WiT, bi, ei, eids, offs, H0, agg1);
        zero_kernel<<<(AGG4 + 255) / 256, 256, 0, stream>>>((f32x4*)agg2, AGG4);
        zero_kernel<<<(AGG4 + 255) / 256, 256, 0, stream>>>((f32x4*)out, AGG4);
        iter_dst_kernel<<<EG, 256, 0, stream>>>(agg1, H0, WhT, bh, ei, rev, eids, offs, agg2);
        iter2F_kernel<<<EG, 256, 0, stream>>>(agg1, agg2, H0, WhT, bh, ei, rev, eids, offs, out);
        flag_kernel<<<NB4, 256, 0, stream>>>(out, flg);
        out_kernel<<<(N_NODES + 63) / 64, 256, 0, stream>>>(x, out, flg, WoT, bo, out);
    } else {
        // ---- LOW fallback ----
        short* H0   = (short*)alloc((size_t)E_EDGES * 128 * 2);
        float* agg1 = (float*)alloc((size_t)N_NODES * 128 * 4);
        float* agg2 = (float*)alloc((size_t)N_NODES * 128 * 4);
        float* flg  = (float*)alloc((size_t)N_NODES * 4);
        short* WiT  = (short*)alloc(128 * 160 * 2);
        short* WhT  = (short*)alloc(128 * 128 * 2);
        short* WoT  = (short*)alloc(128 * 256 * 2);
        float* aggF = out;

        zero_kernel<<<(AGG4 + 255) / 256, 256, 0, stream>>>((f32x4*)agg1, AGG4);
        zero_kernel<<<(AGG4 + 255) / 256, 256, 0, stream>>>((f32x4*)agg2, AGG4);
        zero_kernel<<<(AGG4 + 255) / 256, 256, 0, stream>>>((f32x4*)aggF, AGG4);
        prep_kernel<<<PREPG, 256, 0, stream>>>(Wi, Wh, Wo, WiT, WhT, WoT);
        h0_kernel<<<EG, 256, 0, stream>>>(x, eattr, WiT, bi, ei, H0, agg1);
        iter_atomic_kernel<<<EG, 256, 0, stream>>>(agg1, H0, H0, WhT, bh, ei, rev, agg2);
        iter2c_kernel<<<EG, 256, 0, stream>>>(agg1, agg2, H0, WhT, bh, ei, rev, aggF);
        flag_kernel<<<NB4, 256, 0, stream>>>(aggF, flg);
        out_kernel<<<(N_NODES + 63) / 64, 256, 0, stream>>>(x, aggF, flg, WoT, bo, out);
    }
}

// Round 11
// 613.422 us; speedup vs baseline: 1.0632x; 1.0632x over previous
//
#include <hip/hip_runtime.h>
#include <hip/hip_bf16.h>

#define E_EDGES 600000
#define N_NODES 50000

typedef __attribute__((ext_vector_type(8))) short bf16x8;
typedef __attribute__((ext_vector_type(4))) short s16x4;
typedef __attribute__((ext_vector_type(4))) float f32x4;
typedef unsigned short u16;

static __device__ __forceinline__ float bf2f(u16 u) {
    unsigned int x = ((unsigned int)u) << 16;
    return __builtin_bit_cast(float, x);
}
static __device__ __forceinline__ u16 f2bf(float f) {
    return __builtin_bit_cast(u16, __float2bfloat16(f));
}
static __device__ __forceinline__ int xcd_swz(int orig, int nwg) {
    int q = nwg >> 3, r = nwg & 7;
    int x = orig & 7, o = orig >> 3;
    int base = (x < r) ? x * (q + 1) : r * (q + 1) + (x - r) * q;
    return base + o;
}

__global__ __launch_bounds__(256) void zero_kernel(f32x4* __restrict__ p, int n4) {
    int i = blockIdx.x * 256 + threadIdx.x;
    if (i < n4) p[i] = f32x4{0.f, 0.f, 0.f, 0.f};
}
__global__ __launch_bounds__(256) void zero_int_kernel(int* __restrict__ p, int n) {
    int i = blockIdx.x * 256 + threadIdx.x;
    if (i < n) p[i] = 0;
}

// ---------------- weight prep ----------------
__global__ void prep_kernel(const float* __restrict__ Wi, const float* __restrict__ Wh,
                            const float* __restrict__ Wo,
                            short* __restrict__ WiT, short* __restrict__ WhT,
                            short* __restrict__ WoT) {
    int idx = blockIdx.x * 256 + threadIdx.x;
    if (idx < 128 * 160) {
        int j = idx / 160, k = idx % 160;
        WiT[idx] = (k < 144) ? (short)f2bf(Wi[k * 128 + j]) : (short)0;
    } else if (idx < 128 * 160 + 128 * 128) {
        int t = idx - 128 * 160;
        int j = t / 128, k = t % 128;
        WhT[t] = (short)f2bf(Wh[k * 128 + j]);
    } else if (idx < 128 * 160 + 128 * 128 + 128 * 256) {
        int t = idx - 128 * 160 - 128 * 128;
        int j = t / 256, k = t % 256;
        WoT[t] = (short)f2bf(Wo[k * 128 + j]);
    }
}

// bf16 copies of x and edge_attr (rounding identical to in-kernel cvt)
__global__ __launch_bounds__(256) void prepx_kernel(const float* __restrict__ x,
                                                    const float* __restrict__ ea,
                                                    short* __restrict__ xb,
                                                    short* __restrict__ eb) {
    const int NX4 = N_NODES * 128 / 4;
    const int NE4 = E_EDGES * 16 / 4;
    int i = blockIdx.x * 256 + threadIdx.x;
    if (i < NX4) {
        f32x4 v = ((const f32x4*)x)[i];
        s16x4 o;
#pragma unroll
        for (int j = 0; j < 4; ++j) o[j] = (short)f2bf(v[j]);
        ((s16x4*)xb)[i] = o;
    } else if (i < NX4 + NE4) {
        int t = i - NX4;
        f32x4 v = ((const f32x4*)ea)[t];
        s16x4 o;
#pragma unroll
        for (int j = 0; j < 4; ++j) o[j] = (short)f2bf(v[j]);
        ((s16x4*)eb)[t] = o;
    }
}

// ---------------- CSR build ----------------
__global__ __launch_bounds__(256) void count_kernel(const int* __restrict__ ei,
                                                    int* __restrict__ deg) {
    int e = blockIdx.x * 256 + threadIdx.x;
    if (e < E_EDGES) atomicAdd(&deg[ei[E_EDGES + e]], 1);
}

__global__ __launch_bounds__(1024) void scan_kernel(const int* __restrict__ deg,
                                                    int* __restrict__ offs) {
    __shared__ int wsum[16];
    __shared__ int carry;
    const int t = threadIdx.x, lane = t & 63, wv = t >> 6;
    if (t == 0) { carry = 0; offs[0] = 0; }
    __syncthreads();
    for (int base = 0; base < N_NODES; base += 1024) {
        int i = base + t;
        int v = (i < N_NODES) ? deg[i] : 0;
        int s = v;
#pragma unroll
        for (int o = 1; o < 64; o <<= 1) {
            int u = __shfl_up(s, o, 64);
            if (lane >= o) s += u;
        }
        if (lane == 63) wsum[wv] = s;
        __syncthreads();
        if (wv == 0 && lane < 16) {
            int ws = wsum[lane];
#pragma unroll
            for (int o = 1; o < 16; o <<= 1) {
                int u = __shfl_up(ws, o, 16);
                if (lane >= o) ws += u;
            }
            wsum[lane] = ws;
        }
        __syncthreads();
        int wpre = (wv > 0) ? wsum[wv - 1] : 0;
        int incl = carry + wpre + s;
        if (i < N_NODES) offs[i + 1] = incl;
        __syncthreads();
        if (t == 1023) carry = incl;
        __syncthreads();
    }
}

__global__ __launch_bounds__(256) void scatter_kernel(const int* __restrict__ ei,
                                                      int* __restrict__ offs,
                                                      int* __restrict__ eids) {
    int e = blockIdx.x * 256 + threadIdx.x;
    if (e < E_EDGES) {
        int d = ei[E_EDGES + e];
        int p = atomicAdd(&offs[d], 1);
        eids[p] = e;
    }
}

// ---------------- segment sum via CSR (B path) ----------------
__global__ __launch_bounds__(256) void segsum_kernel(const short* __restrict__ H,
                                                     const int* __restrict__ eids,
                                                     const int* __restrict__ offs,
                                                     float* __restrict__ agg,
                                                     float* __restrict__ flg) {
    const int w = threadIdx.x >> 6, l = threadIdx.x & 63;
    const int n = blockIdx.x * 4 + w;
    if (n >= N_NODES) return;
    int b = (n == 0) ? 0 : offs[n - 1];
    int en = offs[n];
    float s0 = 0.f, s1 = 0.f, t0 = 0.f, t1 = 0.f;
    int j = b;
    for (; j + 2 <= en; j += 2) {
        int e0 = eids[j], e1 = eids[j + 1];
        unsigned int pk0 = *(const unsigned int*)(H + (size_t)e0 * 128 + l * 2);
        unsigned int pk1 = *(const unsigned int*)(H + (size_t)e1 * 128 + l * 2);
        s0 += bf2f((u16)(pk0 & 0xffffu));
        s1 += bf2f((u16)(pk0 >> 16));
        t0 += bf2f((u16)(pk1 & 0xffffu));
        t1 += bf2f((u16)(pk1 >> 16));
    }
    if (j < en) {
        int e0 = eids[j];
        unsigned int pk0 = *(const unsigned int*)(H + (size_t)e0 * 128 + l * 2);
        s0 += bf2f((u16)(pk0 & 0xffffu));
        s1 += bf2f((u16)(pk0 >> 16));
    }
    s0 += t0; s1 += t1;
    agg[(size_t)n * 128 + l * 2] = s0;
    agg[(size_t)n * 128 + l * 2 + 1] = s1;
    if (flg) {
        float s = s0 + s1;
#pragma unroll
        for (int off = 32; off; off >>= 1) s += __shfl_xor(s, off, 64);
        if (l == 0) flg[n] = s;
    }
}

__global__ __launch_bounds__(256) void flag_kernel(const float* __restrict__ agg,
                                                   float* __restrict__ flg) {
    const int w = threadIdx.x >> 6, l = threadIdx.x & 63;
    const int n = blockIdx.x * 4 + w;
    if (n >= N_NODES) return;
    const float* r = agg + (size_t)n * 128 + l * 2;
    float s = r[0] + r[1];
#pragma unroll
    for (int off = 32; off; off >>= 1) s += __shfl_xor(s, off, 64);
    if (l == 0) flg[n] = s;
}

// ---------------- A: dst-ordered H0 + fused segreduce -> agg1 (bf16 inputs) ----------------
__global__ __launch_bounds__(256) void h0dst_kernel(
    const short* __restrict__ xb, const short* __restrict__ eb,
    const short* __restrict__ WiT, const float* __restrict__ bi,
    const int* __restrict__ ei, const int* __restrict__ eids,
    const int* __restrict__ offs, short* __restrict__ H0,
    float* __restrict__ agg1) {
    __shared__ short Bx[128 * 128];  // x-part of Wi, XOR-swizzled
    __shared__ short T[64 * 128];    // swizzled output tile
    __shared__ int eloc[64], dstv[64];
    const int P = xcd_swz(blockIdx.x, gridDim.x) * 64;
    for (int i = threadIdx.x; i < 128 * 16; i += 256) {
        int row = i >> 4, cc = i & 15;
        int dstByte = row * 256 + ((cc * 16) ^ ((row & 7) << 4));
        *(bf16x8*)((char*)Bx + dstByte) = *(const bf16x8*)&WiT[row * 160 + cc * 8];
    }
    if (threadIdx.x < 64) {
        int e = eids[P + threadIdx.x];
        eloc[threadIdx.x] = e;
        dstv[threadIdx.x] = ei[E_EDGES + e];
    }
    __syncthreads();
    const int w = threadIdx.x >> 6, l = threadIdx.x & 63;
    const int c = l & 15, g = l >> 4;
    const int em = eloc[w * 16 + c];
    const int src_e = ei[em];
    const short* xr = xb + (size_t)src_e * 128;
    const short* ar = eb + (size_t)em * 16;

    bf16x8 px[4];
#pragma unroll
    for (int s = 0; s < 4; ++s) px[s] = *(const bf16x8*)(xr + s * 32 + g * 8);
    bf16x8 pe = {0, 0, 0, 0, 0, 0, 0, 0};
    if (g < 2) pe = *(const bf16x8*)(ar + g * 8);
    const int weOff = 128 + (g & 1) * 8;

    f32x4 acc[8] = {};
#pragma unroll
    for (int s = 0; s < 5; ++s) {
        const int k0 = s * 32 + g * 8;
        bf16x8 af = (s < 4) ? px[s] : pe;
#pragma unroll
        for (int nf = 0; nf < 8; ++nf) {
            const int row = nf * 16 + c;
            bf16x8 bfv;
            if (s < 4) {
                int bo = row * 256 + ((k0 * 2) ^ ((row & 7) << 4));
                bfv = *(const bf16x8*)((char*)Bx + bo);
            } else {
                bfv = *(const bf16x8*)&WiT[row * 160 + weOff];
            }
            acc[nf] = __builtin_amdgcn_mfma_f32_16x16x32_bf16(af, bfv, acc[nf], 0, 0, 0);
        }
    }
#pragma unroll
    for (int nf = 0; nf < 8; ++nf) {
        const int col = nf * 16 + c;
        const float bias = bi[col];
#pragma unroll
        for (int r = 0; r < 4; ++r) {
            const int lr2 = w * 16 + g * 4 + r;
            float v = fmaxf(acc[nf][r] + bias, 0.0f);
            int bo = lr2 * 256 + ((col * 2) ^ ((lr2 & 7) << 4));
            *(short*)((char*)T + bo) = (short)f2bf(v);
        }
    }
    __syncthreads();
#pragma unroll
    for (int it = 0; it < 4; ++it) {
        int i = threadIdx.x + it * 256;
        int lr = i >> 4, cc = i & 15;
        int bo = lr * 256 + ((cc * 16) ^ ((lr & 7) << 4));
        *(bf16x8*)&H0[(size_t)eloc[lr] * 128 + cc * 8] = *(const bf16x8*)((char*)T + bo);
    }
    // segmented reduce T -> agg1 (2 halves x 32 rows, all 256 threads)
    {
        const int h = threadIdx.x >> 7;
        const int col = threadIdx.x & 127;
        const int base = h * 32;
        const int Ph = P + base;
        int n0 = dstv[base];
        bool fh0 = (((n0 == 0) ? 0 : offs[n0 - 1]) == Ph);
        bool fh1 = (offs[dstv[base + 31]] == Ph + 32);
        float sum = 0.f;
        int cur = n0, segStart = base;
        for (int lr = base; lr < base + 32; ++lr) {
            int d = dstv[lr];
            int bo = lr * 256 + ((col * 2) ^ ((lr & 7) << 4));
            float v = bf2f(*(const u16*)((char*)T + bo));
            if (d != cur) {
                bool comp = (segStart > base) || fh0;
                float* dp = agg1 + (size_t)cur * 128 + col;
                if (comp) *dp = sum; else atomicAdd(dp, sum);
                cur = d; segStart = lr; sum = v;
            } else {
                sum += v;
            }
        }
        bool comp = ((segStart > base) || fh0) && fh1;
        float* dp = agg1 + (size_t)cur * 128 + col;
        if (comp) *dp = sum; else atomicAdd(dp, sum);
    }
}

// ---------------- A: dst-ordered iteration ----------------
__global__ __launch_bounds__(256) void iter_dst_kernel(
    const float* __restrict__ agg1, const short* __restrict__ H0,
    const short* __restrict__ WhT, const float* __restrict__ bh,
    const int* __restrict__ ei, const int* __restrict__ rev,
    const int* __restrict__ eids, const int* __restrict__ offs,
    float* __restrict__ agg2) {
    __shared__ short B[128 * 136];
    __shared__ short T[64 * 136];
    __shared__ int eloc[64], dstv[64];
    const int P = xcd_swz(blockIdx.x, gridDim.x) * 64;
    for (int i = threadIdx.x; i < 128 * 16; i += 256) {
        int row = i >> 4, cc = i & 15;
        *(bf16x8*)&B[row * 136 + cc * 8] = *(const bf16x8*)&WhT[row * 128 + cc * 8];
    }
    if (threadIdx.x < 64) {
        int e = eids[P + threadIdx.x];
        eloc[threadIdx.x] = e;
        dstv[threadIdx.x] = ei[E_EDGES + e];
    }
    __syncthreads();
    const int w = threadIdx.x >> 6, l = threadIdx.x & 63;
    const int c = l & 15, g = l >> 4;
    const int e_m = eloc[w * 16 + c];
    const int src_e = ei[e_m];
    const int rev_e = rev[e_m];
    const float* arow = agg1 + (size_t)src_e * 128;
    const short* hrow = H0 + (size_t)rev_e * 128;

    bf16x8 stg[4];
#pragma unroll
    for (int it = 0; it < 4; ++it) {
        int i = threadIdx.x + it * 256;
        int lr = i >> 4, cc = i & 15;
        stg[it] = *(const bf16x8*)&H0[(size_t)eloc[lr] * 128 + cc * 8];
    }
    f32x4 pa[4][2];
    bf16x8 ph[4];
#pragma unroll
    for (int s = 0; s < 4; ++s) {
        pa[s][0] = *(const f32x4*)(arow + s * 32 + g * 8);
        pa[s][1] = *(const f32x4*)(arow + s * 32 + g * 8 + 4);
        ph[s] = *(const bf16x8*)(hrow + s * 32 + g * 8);
    }
#pragma unroll
    for (int it = 0; it < 4; ++it) {
        int i = threadIdx.x + it * 256;
        int lr = i >> 4, cc = i & 15;
        *(bf16x8*)&T[lr * 136 + cc * 8] = stg[it];
    }
    __syncthreads();

    f32x4 acc[8] = {};
#pragma unroll
    for (int s = 0; s < 4; ++s) {
        const int k0 = s * 32 + g * 8;
        bf16x8 af;
#pragma unroll
        for (int j = 0; j < 8; ++j) {
            float aj = ((j < 4) ? pa[s][0][j] : pa[s][1][j - 4]) - bf2f((u16)ph[s][j]);
            af[j] = (short)f2bf(aj);
        }
#pragma unroll
        for (int nf = 0; nf < 8; ++nf) {
            bf16x8 bfv = *(const bf16x8*)&B[(nf * 16 + c) * 136 + k0];
            acc[nf] = __builtin_amdgcn_mfma_f32_16x16x32_bf16(af, bfv, acc[nf], 0, 0, 0);
        }
    }
#pragma unroll
    for (int nf = 0; nf < 8; ++nf) {
        const int col = nf * 16 + c;
        const float bias = bh[col];
#pragma unroll
        for (int r = 0; r < 4; ++r) {
            const int lr2 = w * 16 + g * 4 + r;
            float res = bf2f((u16)T[lr2 * 136 + col]);
            float v = fmaxf(acc[nf][r] + bias + res, 0.0f);
            T[lr2 * 136 + col] = (short)f2bf(v);
        }
    }
    __syncthreads();
    {
        const int h = threadIdx.x >> 7;
        const int col = threadIdx.x & 127;
        const int base = h * 32;
        const int Ph = P + base;
        int n0 = dstv[base];
        bool fh0 = (((n0 == 0) ? 0 : offs[n0 - 1]) == Ph);
        bool fh1 = (offs[dstv[base + 31]] == Ph + 32);
        float sum = 0.f;
        int cur = n0, segStart = base;
        for (int lr = base; lr < base + 32; ++lr) {
            int d = dstv[lr];
            float v = bf2f((u16)T[lr * 136 + col]);
            if (d != cur) {
                bool comp = (segStart > base) || fh0;
                float* dp = agg2 + (size_t)cur * 128 + col;
                if (comp) *dp = sum; else atomicAdd(dp, sum);
                cur = d; segStart = lr; sum = v;
            } else {
                sum += v;
            }
        }
        bool comp = ((segStart > base) || fh0) && fh1;
        float* dp = agg2 + (size_t)cur * 128 + col;
        if (comp) *dp = sum; else atomicAdd(dp, sum);
    }
}

// ---------------- A: fused final iteration (r9 body: late scattered residual) ----------------
__global__ __launch_bounds__(256) void iter2F_kernel(
    const float* __restrict__ agg1, const float* __restrict__ agg2,
    const short* __restrict__ H0, const short* __restrict__ WhT,
    const float* __restrict__ bh, const int* __restrict__ ei,
    const int* __restrict__ rev, const int* __restrict__ eids,
    const int* __restrict__ offs, float* __restrict__ aggF) {
    __shared__ short B[128 * 128];   // Wh, XOR-swizzled
    __shared__ short TR[64 * 128];   // swizzled: H0[rev] -> H1[rev] -> H2
    __shared__ int eloc[64], dstv[64], revl[64];
    const int P = xcd_swz(blockIdx.x, gridDim.x) * 64;
    for (int i = threadIdx.x; i < 128 * 16; i += 256) {
        int row = i >> 4, cc = i & 15;
        int dstByte = row * 256 + ((cc * 16) ^ ((row & 7) << 4));
        *(bf16x8*)((char*)B + dstByte) = *(const bf16x8*)&WhT[row * 128 + cc * 8];
    }
    if (threadIdx.x < 64) {
        int e = eids[P + threadIdx.x];
        eloc[threadIdx.x] = e;
        dstv[threadIdx.x] = ei[E_EDGES + e];
        revl[threadIdx.x] = rev[e];
    }
    __syncthreads();
#pragma unroll
    for (int it = 0; it < 4; ++it) {
        int i = threadIdx.x + it * 256;
        int lr = i >> 4, cc = i & 15;
        int bo = lr * 256 + ((cc * 16) ^ ((lr & 7) << 4));
        *(bf16x8*)((char*)TR + bo) = *(const bf16x8*)&H0[(size_t)revl[lr] * 128 + cc * 8];
    }
    const int w = threadIdx.x >> 6, l = threadIdx.x & 63;
    const int c = l & 15, g = l >> 4;
    const int rl = w * 16 + c;
    const int em = eloc[rl];
    const int dst_em = dstv[rl];
    const int src_m = ei[em];
    const short* h0row = H0 + (size_t)em * 128;
    const float* a1row = agg1 + (size_t)dst_em * 128;
    const float* a2row = agg2 + (size_t)src_m * 128;

    bf16x8 ph[4];
    f32x4 pa1[4][2], pa2[4][2];
#pragma unroll
    for (int s = 0; s < 4; ++s) {
        ph[s] = *(const bf16x8*)(h0row + s * 32 + g * 8);
        pa1[s][0] = *(const f32x4*)(a1row + s * 32 + g * 8);
        pa1[s][1] = *(const f32x4*)(a1row + s * 32 + g * 8 + 4);
        pa2[s][0] = *(const f32x4*)(a2row + s * 32 + g * 8);
        pa2[s][1] = *(const f32x4*)(a2row + s * 32 + g * 8 + 4);
    }
    __syncthreads();

    // phase 1: H1[rev_em] = relu(H0[rev_em] + (agg1[dst_em] - H0[em]) @ Wh + bh)
    f32x4 acc[8] = {};
#pragma unroll
    for (int s = 0; s < 4; ++s) {
        const int k0 = s * 32 + g * 8;
        bf16x8 af;
#pragma unroll
        for (int j = 0; j < 8; ++j) {
            float aj = ((j < 4) ? pa1[s][0][j] : pa1[s][1][j - 4]) - bf2f((u16)ph[s][j]);
            af[j] = (short)f2bf(aj);
        }
#pragma unroll
        for (int nf = 0; nf < 8; ++nf) {
            const int row = nf * 16 + c;
            int bo = row * 256 + ((k0 * 2) ^ ((row & 7) << 4));
            bf16x8 bfv = *(const bf16x8*)((char*)B + bo);
            acc[nf] = __builtin_amdgcn_mfma_f32_16x16x32_bf16(af, bfv, acc[nf], 0, 0, 0);
        }
    }
#pragma unroll
    for (int nf = 0; nf < 8; ++nf) {
        const int col = nf * 16 + c;
        const float bias = bh[col];
#pragma unroll
        for (int r = 0; r < 4; ++r) {
            const int lr2 = w * 16 + g * 4 + r;
            int bo = lr2 * 256 + ((col * 2) ^ ((lr2 & 7) << 4));
            float res = bf2f(*(const u16*)((char*)TR + bo));
            float v = fmaxf(acc[nf][r] + bias + res, 0.0f);
            *(short*)((char*)TR + bo) = (short)f2bf(v);
        }
    }
    __syncthreads();
    // phase 2: H2[em] = relu(H0[em] + (agg2[src_em] - H1[rev_em]) @ Wh + bh)
    f32x4 acc2[8] = {};
#pragma unroll
    for (int s = 0; s < 4; ++s) {
        const int k0 = s * 32 + g * 8;
        int boT = rl * 256 + ((k0 * 2) ^ ((rl & 7) << 4));
        bf16x8 hv = *(const bf16x8*)((char*)TR + boT);
        bf16x8 af;
#pragma unroll
        for (int j = 0; j < 8; ++j) {
            float aj = ((j < 4) ? pa2[s][0][j] : pa2[s][1][j - 4]) - bf2f((u16)hv[j]);
            af[j] = (short)f2bf(aj);
        }
#pragma unroll
        for (int nf = 0; nf < 8; ++nf) {
            const int row = nf * 16 + c;
            int bo = row * 256 + ((k0 * 2) ^ ((row & 7) << 4));
            bf16x8 bfv = *(const bf16x8*)((char*)B + bo);
            acc2[nf] = __builtin_amdgcn_mfma_f32_16x16x32_bf16(af, bfv, acc2[nf], 0, 0, 0);
        }
    }
    __syncthreads();  // all H1 reads complete before overwriting TR with H2
#pragma unroll
    for (int nf = 0; nf < 8; ++nf) {
        const int col = nf * 16 + c;
        const float bias = bh[col];
#pragma unroll
        for (int r = 0; r < 4; ++r) {
            const int lr2 = w * 16 + g * 4 + r;
            float res = bf2f((u16)H0[(size_t)eloc[lr2] * 128 + col]);
            float v = fmaxf(acc2[nf][r] + bias + res, 0.0f);
            int bo = lr2 * 256 + ((col * 2) ^ ((lr2 & 7) << 4));
            *(short*)((char*)TR + bo) = (short)f2bf(v);
        }
    }
    __syncthreads();
    {
        const int h = threadIdx.x >> 7;
        const int col = threadIdx.x & 127;
        const int base = h * 32;
        const int Ph = P + base;
        int n0 = dstv[base];
        bool fh0 = (((n0 == 0) ? 0 : offs[n0 - 1]) == Ph);
        bool fh1 = (offs[dstv[base + 31]] == Ph + 32);
        float sum = 0.f;
        int cur = n0, segStart = base;
        for (int lr = base; lr < base + 32; ++lr) {
            int d = dstv[lr];
            int bo = lr * 256 + ((col * 2) ^ ((lr & 7) << 4));
            float v = bf2f(*(const u16*)((char*)TR + bo));
            if (d != cur) {
                bool comp = (segStart > base) || fh0;
                float* dp = aggF + (size_t)cur * 128 + col;
                if (comp) *dp = sum; else atomicAdd(dp, sum);
                cur = d; segStart = lr; sum = v;
            } else {
                sum += v;
            }
        }
        bool comp = ((segStart > base) || fh0) && fh1;
        float* dp = aggF + (size_t)cur * 128 + col;
        if (comp) *dp = sum; else atomicAdd(dp, sum);
    }
}

// ---------------- B-path kernels (unchanged) ----------------
__global__ __launch_bounds__(256) void h0s_kernel(
    const float* __restrict__ x, const float* __restrict__ eattr,
    const short* __restrict__ WiT, const float* __restrict__ bi,
    const int* __restrict__ ei, short* __restrict__ H0) {
    __shared__ short B[128 * 168];
    for (int i = threadIdx.x; i < 128 * 20; i += 256) {
        int row = i / 20, cc = i % 20;
        *(bf16x8*)&B[row * 168 + cc * 8] = *(const bf16x8*)&WiT[row * 160 + cc * 8];
    }
    __syncthreads();
    const int w = threadIdx.x >> 6, l = threadIdx.x & 63;
    const int c = l & 15, g = l >> 4;
    const int e0 = blockIdx.x * 64 + w * 16;
    const int em = e0 + c;
    const int src_e = ei[em];
    const float* xr = x + (size_t)src_e * 128;
    const float* ar = eattr + (size_t)em * 16;

    f32x4 acc[8] = {};
#pragma unroll
    for (int s = 0; s < 5; ++s) {
        const int k0 = s * 32 + g * 8;
        float av[8];
        if (s < 4) {
            f32x4 p0 = *(const f32x4*)(xr + k0);
            f32x4 p1 = *(const f32x4*)(xr + k0 + 4);
#pragma unroll
            for (int j = 0; j < 4; ++j) { av[j] = p0[j]; av[j + 4] = p1[j]; }
        } else {
            if (g < 2) {
                f32x4 p0 = *(const f32x4*)(ar + g * 8);
                f32x4 p1 = *(const f32x4*)(ar + g * 8 + 4);
#pragma unroll
                for (int j = 0; j < 4; ++j) { av[j] = p0[j]; av[j + 4] = p1[j]; }
            } else {
#pragma unroll
                for (int j = 0; j < 8; ++j) av[j] = 0.f;
            }
        }
        bf16x8 af;
#pragma unroll
        for (int j = 0; j < 8; ++j) af[j] = (short)f2bf(av[j]);
#pragma unroll
        for (int nf = 0; nf < 8; ++nf) {
            bf16x8 bfv = *(const bf16x8*)&B[(nf * 16 + c) * 168 + k0];
            acc[nf] = __builtin_amdgcn_mfma_f32_16x16x32_bf16(af, bfv, acc[nf], 0, 0, 0);
        }
    }
#pragma unroll
    for (int nf = 0; nf < 8; ++nf) {
        const int col = nf * 16 + c;
        const float bias = bi[col];
#pragma unroll
        for (int r = 0; r < 4; ++r) {
            const int er = e0 + g * 4 + r;
            float v = fmaxf(acc[nf][r] + bias, 0.0f);
            H0[(size_t)er * 128 + col] = (short)f2bf(v);
        }
    }
}

__global__ __launch_bounds__(256) void iterx_kernel(
    const float* __restrict__ agg, const short* __restrict__ Hrev,
    const short* Hres, const short* __restrict__ WhT,
    const float* __restrict__ bh, const int* __restrict__ ei,
    const int* __restrict__ rev, short* Hout) {
    __shared__ short B[128 * 136];
    for (int i = threadIdx.x; i < 128 * 16; i += 256) {
        int row = i >> 4, cc = i & 15;
        *(bf16x8*)&B[row * 136 + cc * 8] = *(const bf16x8*)&WhT[row * 128 + cc * 8];
    }
    __syncthreads();
    const int w = threadIdx.x >> 6, l = threadIdx.x & 63;
    const int c = l & 15, g = l >> 4;
    const int e0 = blockIdx.x * 64 + w * 16;
    const int em = e0 + c;
    const int src_e = ei[em];
    const int rev_e = rev[em];
    const float* arow = agg + (size_t)src_e * 128;
    const short* hrow = Hrev + (size_t)rev_e * 128;

    f32x4 acc[8] = {};
#pragma unroll
    for (int s = 0; s < 4; ++s) {
        const int k0 = s * 32 + g * 8;
        f32x4 p0 = *(const f32x4*)(arow + k0);
        f32x4 p1 = *(const f32x4*)(arow + k0 + 4);
        bf16x8 hv = *(const bf16x8*)(hrow + k0);
        bf16x8 af;
#pragma unroll
        for (int j = 0; j < 8; ++j) {
            float aj = ((j < 4) ? p0[j] : p1[j - 4]) - bf2f((u16)hv[j]);
            af[j] = (short)f2bf(aj);
        }
#pragma unroll
        for (int nf = 0; nf < 8; ++nf) {
            bf16x8 bfv = *(const bf16x8*)&B[(nf * 16 + c) * 136 + k0];
            acc[nf] = __builtin_amdgcn_mfma_f32_16x16x32_bf16(af, bfv, acc[nf], 0, 0, 0);
        }
    }
#pragma unroll
    for (int nf = 0; nf < 8; ++nf) {
        const int col = nf * 16 + c;
        const float bias = bh[col];
#pragma unroll
        for (int r = 0; r < 4; ++r) {
            const int er = e0 + g * 4 + r;
            float v = acc[nf][r] + bias + bf2f((u16)Hres[(size_t)er * 128 + col]);
            v = fmaxf(v, 0.0f);
            Hout[(size_t)er * 128 + col] = (short)f2bf(v);
        }
    }
}

// ---------------- LOW-fallback kernels ----------------
__global__ __launch_bounds__(256) void h0_kernel(
    const float* __restrict__ x, const float* __restrict__ eattr,
    const short* __restrict__ WiT, const float* __restrict__ bi,
    const int* __restrict__ ei, short* __restrict__ H0, float* __restrict__ agg) {
    __shared__ short B[128 * 168];
    for (int i = threadIdx.x; i < 128 * 20; i += 256) {
        int row = i / 20, cc = i % 20;
        *(bf16x8*)&B[row * 168 + cc * 8] = *(const bf16x8*)&WiT[row * 160 + cc * 8];
    }
    __syncthreads();
    const int w = threadIdx.x >> 6, l = threadIdx.x & 63;
    const int c = l & 15, g = l >> 4;
    const int e0 = blockIdx.x * 64 + w * 16;
    const int em = e0 + c;
    const int src_e = ei[em];
    const float* xr = x + (size_t)src_e * 128;
    const float* ar = eattr + (size_t)em * 16;
    f32x4 acc[8] = {};
#pragma unroll
    for (int s = 0; s < 5; ++s) {
        const int k0 = s * 32 + g * 8;
        float av[8];
        if (s < 4) {
            f32x4 p0 = *(const f32x4*)(xr + k0);
            f32x4 p1 = *(const f32x4*)(xr + k0 + 4);
#pragma unroll
            for (int j = 0; j < 4; ++j) { av[j] = p0[j]; av[j + 4] = p1[j]; }
        } else {
            if (g < 2) {
                f32x4 p0 = *(const f32x4*)(ar + g * 8);
                f32x4 p1 = *(const f32x4*)(ar + g * 8 + 4);
#pragma unroll
                for (int j = 0; j < 4; ++j) { av[j] = p0[j]; av[j + 4] = p1[j]; }
            } else {
#pragma unroll
                for (int j = 0; j < 8; ++j) av[j] = 0.f;
            }
        }
        bf16x8 af;
#pragma unroll
        for (int j = 0; j < 8; ++j) af[j] = (short)f2bf(av[j]);
#pragma unroll
        for (int nf = 0; nf < 8; ++nf) {
            bf16x8 bfv = *(const bf16x8*)&B[(nf * 16 + c) * 168 + k0];
            acc[nf] = __builtin_amdgcn_mfma_f32_16x16x32_bf16(af, bfv, acc[nf], 0, 0, 0);
        }
    }
    int dsts[4];
#pragma unroll
    for (int r = 0; r < 4; ++r) dsts[r] = ei[E_EDGES + e0 + g * 4 + r];
#pragma unroll
    for (int nf = 0; nf < 8; ++nf) {
        const int col = nf * 16 + c;
        const float bias = bi[col];
#pragma unroll
        for (int r = 0; r < 4; ++r) {
            const int er = e0 + g * 4 + r;
            float v = fmaxf(acc[nf][r] + bias, 0.0f);
            u16 hb = f2bf(v);
            H0[(size_t)er * 128 + col] = (short)hb;
            atomicAdd(agg + (size_t)dsts[r] * 128 + col, bf2f(hb));
        }
    }
}

__global__ __launch_bounds__(256) void iter_atomic_kernel(
    const float* __restrict__ aggin, const short* __restrict__ Hin,
    const short* __restrict__ H0, const short* __restrict__ WhT,
    const float* __restrict__ bh, const int* __restrict__ ei,
    const int* __restrict__ rev, float* __restrict__ aggout) {
    __shared__ short B[128 * 136];
    for (int i = threadIdx.x; i < 128 * 16; i += 256) {
        int row = i >> 4, cc = i & 15;
        *(bf16x8*)&B[row * 136 + cc * 8] = *(const bf16x8*)&WhT[row * 128 + cc * 8];
    }
    __syncthreads();
    const int w = threadIdx.x >> 6, l = threadIdx.x & 63;
    const int c = l & 15, g = l >> 4;
    const int e0 = blockIdx.x * 64 + w * 16;
    const int em = e0 + c;
    const int src_e = ei[em];
    const int rev_e = rev[em];
    const float* arow = aggin + (size_t)src_e * 128;
    const short* hrow = Hin + (size_t)rev_e * 128;

    f32x4 acc[8] = {};
#pragma unroll
    for (int s = 0; s < 4; ++s) {
        const int k0 = s * 32 + g * 8;
        f32x4 p0 = *(const f32x4*)(arow + k0);
        f32x4 p1 = *(const f32x4*)(arow + k0 + 4);
        bf16x8 hv = *(const bf16x8*)(hrow + k0);
        bf16x8 af;
#pragma unroll
        for (int j = 0; j < 8; ++j) {
            float aj = ((j < 4) ? p0[j] : p1[j - 4]) - bf2f((u16)hv[j]);
            af[j] = (short)f2bf(aj);
        }
#pragma unroll
        for (int nf = 0; nf < 8; ++nf) {
            bf16x8 bfv = *(const bf16x8*)&B[(nf * 16 + c) * 136 + k0];
            acc[nf] = __builtin_amdgcn_mfma_f32_16x16x32_bf16(af, bfv, acc[nf], 0, 0, 0);
        }
    }
    int dsts[4];
#pragma unroll
    for (int r = 0; r < 4; ++r) dsts[r] = ei[E_EDGES + e0 + g * 4 + r];
#pragma unroll
    for (int nf = 0; nf < 8; ++nf) {
        const int col = nf * 16 + c;
        const float bias = bh[col];
#pragma unroll
        for (int r = 0; r < 4; ++r) {
            const int er = e0 + g * 4 + r;
            float v = acc[nf][r] + bias + bf2f((u16)H0[(size_t)er * 128 + col]);
            v = fmaxf(v, 0.0f);
            atomicAdd(aggout + (size_t)dsts[r] * 128 + col, bf2f(f2bf(v)));
        }
    }
}

__global__ __launch_bounds__(256) void iter2c_kernel(
    const float* __restrict__ agg1, const float* __restrict__ agg2,
    const short* __restrict__ H0, const short* __restrict__ WhT,
    const float* __restrict__ bh, const int* __restrict__ ei,
    const int* __restrict__ rev, float* __restrict__ aggF) {
    __shared__ short B[128 * 136];
    __shared__ short T[4][16 * 136];
    for (int i = threadIdx.x; i < 128 * 16; i += 256) {
        int row = i >> 4, cc = i & 15;
        *(bf16x8*)&B[row * 136 + cc * 8] = *(const bf16x8*)&WhT[row * 128 + cc * 8];
    }
    __syncthreads();
    const int w = threadIdx.x >> 6, l = threadIdx.x & 63;
    const int c = l & 15, g = l >> 4;
    const int e0 = blockIdx.x * 64 + w * 16;
    const int em = e0 + c;
    const int dst_em = ei[E_EDGES + em];
    const int src_em = ei[em];
    const float* a1row = agg1 + (size_t)dst_em * 128;
    const float* a2row = agg2 + (size_t)src_em * 128;
    const short* h0row = H0 + (size_t)em * 128;
    int rows[4], revs[4], dsts[4];
#pragma unroll
    for (int r = 0; r < 4; ++r) {
        rows[r] = e0 + g * 4 + r;
        revs[r] = rev[rows[r]];
        dsts[r] = ei[E_EDGES + rows[r]];
    }
    f32x4 acc[8] = {};
#pragma unroll
    for (int s = 0; s < 4; ++s) {
        const int k0 = s * 32 + g * 8;
        f32x4 p0 = *(const f32x4*)(a1row + k0);
        f32x4 p1 = *(const f32x4*)(a1row + k0 + 4);
        bf16x8 hv = *(const bf16x8*)(h0row + k0);
        bf16x8 af;
#pragma unroll
        for (int j = 0; j < 8; ++j) {
            float aj = ((j < 4) ? p0[j] : p1[j - 4]) - bf2f((u16)hv[j]);
            af[j] = (short)f2bf(aj);
        }
#pragma unroll
        for (int nf = 0; nf < 8; ++nf) {
            bf16x8 bfv = *(const bf16x8*)&B[(nf * 16 + c) * 136 + k0];
            acc[nf] = __builtin_amdgcn_mfma_f32_16x16x32_bf16(af, bfv, acc[nf], 0, 0, 0);
        }
    }
#pragma unroll
    for (int nf = 0; nf < 8; ++nf) {
        const int col = nf * 16 + c;
        const float bias = bh[col];
#pragma unroll
        for (int r = 0; r < 4; ++r) {
            float res = bf2f((u16)H0[(size_t)revs[r] * 128 + col]);
            float v = fmaxf(acc[nf][r] + bias + res, 0.0f);
            T[w][(g * 4 + r) * 136 + col] = (short)f2bf(v);
        }
    }
    __syncthreads();
    f32x4 acc2[8] = {};
#pragma unroll
    for (int s = 0; s < 4; ++s) {
        const int k0 = s * 32 + g * 8;
        f32x4 p0 = *(const f32x4*)(a2row + k0);
        f32x4 p1 = *(const f32x4*)(a2row + k0 + 4);
        bf16x8 hv = *(const bf16x8*)&T[w][c * 136 + k0];
        bf16x8 af;
#pragma unroll
        for (int j = 0; j < 8; ++j) {
            float aj = ((j < 4) ? p0[j] : p1[j - 4]) - bf2f((u16)hv[j]);
            af[j] = (short)f2bf(aj);
        }
#pragma unroll
        for (int nf = 0; nf < 8; ++nf) {
            bf16x8 bfv = *(const bf16x8*)&B[(nf * 16 + c) * 136 + k0];
            acc2[nf] = __builtin_amdgcn_mfma_f32_16x16x32_bf16(af, bfv, acc2[nf], 0, 0, 0);
        }
    }
#pragma unroll
    for (int nf = 0; nf < 8; ++nf) {
        const int col = nf * 16 + c;
        const float bias = bh[col];
#pragma unroll
        for (int r = 0; r < 4; ++r) {
            float res = bf2f((u16)H0[(size_t)rows[r] * 128 + col]);
            float v = fmaxf(acc2[nf][r] + bias + res, 0.0f);
            atomicAdd(aggF + (size_t)dsts[r] * 128 + col, v);
        }
    }
}

// ---------------- output ----------------
__global__ __launch_bounds__(256) void out_kernel(
    const float* __restrict__ x, const float* agg,
    const float* __restrict__ flg, const short* __restrict__ WoT,
    const float* __restrict__ bo, float* out) {
    __shared__ short B[128 * 256];
    for (int i = threadIdx.x; i < 128 * 32; i += 256) {
        int row = i >> 5, cc = i & 31;
        int dstByte = row * 512 + ((cc * 16) ^ ((row & 7) << 4));
        *(bf16x8*)((char*)B + dstByte) = *(const bf16x8*)&WoT[row * 256 + cc * 8];
    }
    __syncthreads();
    const int w = threadIdx.x >> 6, l = threadIdx.x & 63;
    const int c = l & 15, g = l >> 4;
    const int n0 = blockIdx.x * 64 + w * 16;
    const int nm = n0 + c;
    const int nmc = nm < N_NODES ? nm : N_NODES - 1;
    const float* xr = x + (size_t)nmc * 128;
    const float* mr = agg + (size_t)nmc * 128;
    const bool usex = (flg[nmc] == 0.0f);
    f32x4 acc[8] = {};
#pragma unroll
    for (int s = 0; s < 8; ++s) {
        const int k0 = s * 32 + g * 8;
        const float* srcp;
        int kk;
        if (s < 4) { srcp = xr; kk = k0; }
        else       { srcp = usex ? xr : mr; kk = k0 - 128; }
        f32x4 p0 = *(const f32x4*)(srcp + kk);
        f32x4 p1 = *(const f32x4*)(srcp + kk + 4);
        bf16x8 af;
#pragma unroll
        for (int j = 0; j < 4; ++j) {
            af[j] = (short)f2bf(p0[j]);
            af[j + 4] = (short)f2bf(p1[j]);
        }
#pragma unroll
        for (int nf = 0; nf < 8; ++nf) {
            int row = nf * 16 + c;
            int byteOff = row * 512 + ((k0 * 2) ^ ((row & 7) << 4));
            bf16x8 bfv = *(const bf16x8*)((char*)B + byteOff);
            acc[nf] = __builtin_amdgcn_mfma_f32_16x16x32_bf16(af, bfv, acc[nf], 0, 0, 0);
        }
    }
#pragma unroll
    for (int nf = 0; nf < 8; ++nf) {
        const int col = nf * 16 + c;
        const float bias = bo[col];
#pragma unroll
        for (int r = 0; r < 4; ++r) {
            const int er = n0 + g * 4 + r;
            if (er < N_NODES) {
                float v = fmaxf(acc[nf][r] + bias, 0.0f);
                out[(size_t)er * 128 + col] = v;
            }
        }
    }
}

extern "C" void kernel_launch(void* const* d_in, const int* in_sizes, int n_in,
                              void* d_out, int out_size, void* d_ws, size_t ws_size,
                              hipStream_t stream) {
    const float* x     = (const float*)d_in[0];
    const float* eattr = (const float*)d_in[1];
    const float* Wi    = (const float*)d_in[2];
    const float* bi    = (const float*)d_in[3];
    const float* Wh    = (const float*)d_in[4];
    const float* bh    = (const float*)d_in[5];
    const float* Wo    = (const float*)d_in[6];
    const float* bo    = (const float*)d_in[7];
    const int*   ei    = (const int*)d_in[8];
    const int*   rev   = (const int*)d_in[9];
    float* out = (float*)d_out;
    (void)in_sizes; (void)n_in; (void)out_size;

    char* ws = (char*)d_ws;
    size_t off = 0;
    auto alloc = [&](size_t bytes) {
        void* p = ws + off;
        off = (off + bytes + 255) & ~(size_t)255;
        return p;
    };
    const int AGG4 = N_NODES * 128 / 4;
    const int EG = E_EDGES / 64;           // 9375
    const int EB = (E_EDGES + 255) / 256;  // 2344
    const int NB4 = (N_NODES + 3) / 4;     // 12500
    const int PREPG = (128 * 160 + 128 * 128 + 128 * 256 + 255) / 256;
    const int PREPXG = (N_NODES * 128 / 4 + E_EDGES * 16 / 4 + 255) / 256;

    if (ws_size >= (size_t)337 * 1000 * 1000) {
        // ---- Option B: fully streaming ----
        short* H0  = (short*)alloc((size_t)E_EDGES * 128 * 2);
        short* H1  = (short*)alloc((size_t)E_EDGES * 128 * 2);
        float* agg = (float*)alloc((size_t)N_NODES * 128 * 4);
        float* flg = (float*)alloc((size_t)N_NODES * 4);
        short* WiT = (short*)alloc(128 * 160 * 2);
        short* WhT = (short*)alloc(128 * 128 * 2);
        short* WoT = (short*)alloc(128 * 256 * 2);
        int* deg   = (int*)alloc((size_t)N_NODES * 4);
        int* offs  = (int*)alloc((size_t)(N_NODES + 1) * 4);
        int* eids  = (int*)alloc((size_t)E_EDGES * 4);

        zero_int_kernel<<<(N_NODES + 255) / 256, 256, 0, stream>>>(deg, N_NODES);
        prep_kernel<<<PREPG, 256, 0, stream>>>(Wi, Wh, Wo, WiT, WhT, WoT);
        count_kernel<<<EB, 256, 0, stream>>>(ei, deg);
        scan_kernel<<<1, 1024, 0, stream>>>(deg, offs);
        scatter_kernel<<<EB, 256, 0, stream>>>(ei, offs, eids);
        h0s_kernel<<<EG, 256, 0, stream>>>(x, eattr, WiT, bi, ei, H0);
        segsum_kernel<<<NB4, 256, 0, stream>>>(H0, eids, offs, agg, nullptr);
        iterx_kernel<<<EG, 256, 0, stream>>>(agg, H0, H0, WhT, bh, ei, rev, H1);
        segsum_kernel<<<NB4, 256, 0, stream>>>(H1, eids, offs, agg, nullptr);
        iterx_kernel<<<EG, 256, 0, stream>>>(agg, H1, H0, WhT, bh, ei, rev, H0);
        segsum_kernel<<<NB4, 256, 0, stream>>>(H0, eids, offs, out, flg);
        out_kernel<<<(N_NODES + 63) / 64, 256, 0, stream>>>(x, out, flg, WoT, bo, out);
    } else if (ws_size >= (size_t)210 * 1000 * 1000) {
        // ---- Option A (r11): r9 iter2F + bf16-input h0dst via prepx ----
        short* H0   = (short*)alloc((size_t)E_EDGES * 128 * 2);
        float* agg1 = (float*)alloc((size_t)N_NODES * 128 * 4);
        float* agg2 = (float*)alloc((size_t)N_NODES * 128 * 4);
        float* flg  = (float*)alloc((size_t)N_NODES * 4);
        short* WiT  = (short*)alloc(128 * 160 * 2);
        short* WhT  = (short*)alloc(128 * 128 * 2);
        short* WoT  = (short*)alloc(128 * 256 * 2);
        int* deg    = (int*)alloc((size_t)N_NODES * 4);
        int* offs   = (int*)alloc((size_t)(N_NODES + 1) * 4);
        int* eids   = (int*)alloc((size_t)E_EDGES * 4);
        short* xbuf = (short*)agg2;   // alias: dead until after h0dst
        short* ebuf = (short*)out;    // alias: zeroed after h0dst

        zero_int_kernel<<<(N_NODES + 255) / 256, 256, 0, stream>>>(deg, N_NODES);
        zero_kernel<<<(AGG4 + 255) / 256, 256, 0, stream>>>((f32x4*)agg1, AGG4);
        prep_kernel<<<PREPG, 256, 0, stream>>>(Wi, Wh, Wo, WiT, WhT, WoT);
        prepx_kernel<<<PREPXG, 256, 0, stream>>>(x, eattr, xbuf, ebuf);
        count_kernel<<<EB, 256, 0, stream>>>(ei, deg);
        scan_kernel<<<1, 1024, 0, stream>>>(deg, offs);
        scatter_kernel<<<EB, 256, 0, stream>>>(ei, offs, eids);
        h0dst_kernel<<<EG, 256, 0, stream>>>(xbuf, ebuf, WiT, bi, ei, eids, offs, H0, agg1);
        zero_kernel<<<(AGG4 + 255) / 256, 256, 0, stream>>>((f32x4*)agg2, AGG4);
        zero_kernel<<<(AGG4 + 255) / 256, 256, 0, stream>>>((f32x4*)out, AGG4);
        iter_dst_kernel<<<EG, 256, 0, stream>>>(agg1, H0, WhT, bh, ei, rev, eids, offs, agg2);
        iter2F_kernel<<<EG, 256, 0, stream>>>(agg1, agg2, H0, WhT, bh, ei, rev, eids, offs, out);
        flag_kernel<<<NB4, 256, 0, stream>>>(out, flg);
        out_kernel<<<(N_NODES + 63) / 64, 256, 0, stream>>>(x, out, flg, WoT, bo, out);
    } else {
        // ---- LOW fallback ----
        short* H0   = (short*)alloc((size_t)E_EDGES * 128 * 2);
        float* agg1 = (float*)alloc((size_t)N_NODES * 128 * 4);
        float* agg2 = (float*)alloc((size_t)N_NODES * 128 * 4);
        float* flg  = (float*)alloc((size_t)N_NODES * 4);
        short* WiT  = (short*)alloc(128 * 160 * 2);
        short* WhT  = (short*)alloc(128 * 128 * 2);
        short* WoT  = (short*)alloc(128 * 256 * 2);
        float* aggF = out;

        zero_kernel<<<(AGG4 + 255) / 256, 256, 0, stream>>>((f32x4*)agg1, AGG4);
        zero_kernel<<<(AGG4 + 255) / 256, 256, 0, stream>>>((f32x4*)agg2, AGG4);
        zero_kernel<<<(AGG4 + 255) / 256, 256, 0, stream>>>((f32x4*)aggF, AGG4);
        prep_kernel<<<PREPG, 256, 0, stream>>>(Wi, Wh, Wo, WiT, WhT, WoT);
        h0_kernel<<<EG, 256, 0, stream>>>(x, eattr, WiT, bi, ei, H0, agg1);
        iter_atomic_kernel<<<EG, 256, 0, stream>>>(agg1, H0, H0, WhT, bh, ei, rev, agg2);
        iter2c_kernel<<<EG, 256, 0, stream>>>(agg1, agg2, H0, WhT, bh, ei, rev, aggF);
        flag_kernel<<<NB4, 256, 0, stream>>>(aggF, flg);
        out_kernel<<<(N_NODES + 63) / 64, 256, 0, stream>>>(x, aggF, flg, WoT, bo, out);
    }
}

// Round 12
// 610.014 us; speedup vs baseline: 1.0692x; 1.0056x over previous
//
#include <hip/hip_runtime.h>
#include <hip/hip_bf16.h>

#define E_EDGES 600000
#define N_NODES 50000

typedef __attribute__((ext_vector_type(8))) short bf16x8;
typedef __attribute__((ext_vector_type(4))) short s16x4;
typedef __attribute__((ext_vector_type(4))) float f32x4;
typedef unsigned short u16;

static __device__ __forceinline__ float bf2f(u16 u) {
    unsigned int x = ((unsigned int)u) << 16;
    return __builtin_bit_cast(float, x);
}
static __device__ __forceinline__ u16 f2bf(float f) {
    return __builtin_bit_cast(u16, __float2bfloat16(f));
}
static __device__ __forceinline__ int xcd_swz(int orig, int nwg) {
    int q = nwg >> 3, r = nwg & 7;
    int x = orig & 7, o = orig >> 3;
    int base = (x < r) ? x * (q + 1) : r * (q + 1) + (x - r) * q;
    return base + o;
}

__global__ __launch_bounds__(256) void zero_kernel(f32x4* __restrict__ p, int n4) {
    int i = blockIdx.x * 256 + threadIdx.x;
    if (i < n4) p[i] = f32x4{0.f, 0.f, 0.f, 0.f};
}
__global__ __launch_bounds__(256) void zero_int_kernel(int* __restrict__ p, int n) {
    int i = blockIdx.x * 256 + threadIdx.x;
    if (i < n) p[i] = 0;
}

// ---------------- weight prep ----------------
__global__ void prep_kernel(const float* __restrict__ Wi, const float* __restrict__ Wh,
                            const float* __restrict__ Wo,
                            short* __restrict__ WiT, short* __restrict__ WhT,
                            short* __restrict__ WoT) {
    int idx = blockIdx.x * 256 + threadIdx.x;
    if (idx < 128 * 160) {
        int j = idx / 160, k = idx % 160;
        WiT[idx] = (k < 144) ? (short)f2bf(Wi[k * 128 + j]) : (short)0;
    } else if (idx < 128 * 160 + 128 * 128) {
        int t = idx - 128 * 160;
        int j = t / 128, k = t % 128;
        WhT[t] = (short)f2bf(Wh[k * 128 + j]);
    } else if (idx < 128 * 160 + 128 * 128 + 128 * 256) {
        int t = idx - 128 * 160 - 128 * 128;
        int j = t / 256, k = t % 256;
        WoT[t] = (short)f2bf(Wo[k * 128 + j]);
    }
}

// bf16 copies of x and edge_attr
__global__ __launch_bounds__(256) void prepx_kernel(const float* __restrict__ x,
                                                    const float* __restrict__ ea,
                                                    short* __restrict__ xb,
                                                    short* __restrict__ eb) {
    const int NX4 = N_NODES * 128 / 4;
    const int NE4 = E_EDGES * 16 / 4;
    int i = blockIdx.x * 256 + threadIdx.x;
    if (i < NX4) {
        f32x4 v = ((const f32x4*)x)[i];
        s16x4 o;
#pragma unroll
        for (int j = 0; j < 4; ++j) o[j] = (short)f2bf(v[j]);
        ((s16x4*)xb)[i] = o;
    } else if (i < NX4 + NE4) {
        int t = i - NX4;
        f32x4 v = ((const f32x4*)ea)[t];
        s16x4 o;
#pragma unroll
        for (int j = 0; j < 4; ++j) o[j] = (short)f2bf(v[j]);
        ((s16x4*)eb)[t] = o;
    }
}

// ---------------- CSR build ----------------
__global__ __launch_bounds__(256) void count_kernel(const int* __restrict__ ei,
                                                    int* __restrict__ deg) {
    int e = blockIdx.x * 256 + threadIdx.x;
    if (e < E_EDGES) atomicAdd(&deg[ei[E_EDGES + e]], 1);
}

__global__ __launch_bounds__(1024) void scan_kernel(const int* __restrict__ deg,
                                                    int* __restrict__ offs) {
    __shared__ int wsum[16];
    __shared__ int carry;
    const int t = threadIdx.x, lane = t & 63, wv = t >> 6;
    if (t == 0) { carry = 0; offs[0] = 0; }
    __syncthreads();
    for (int base = 0; base < N_NODES; base += 1024) {
        int i = base + t;
        int v = (i < N_NODES) ? deg[i] : 0;
        int s = v;
#pragma unroll
        for (int o = 1; o < 64; o <<= 1) {
            int u = __shfl_up(s, o, 64);
            if (lane >= o) s += u;
        }
        if (lane == 63) wsum[wv] = s;
        __syncthreads();
        if (wv == 0 && lane < 16) {
            int ws = wsum[lane];
#pragma unroll
            for (int o = 1; o < 16; o <<= 1) {
                int u = __shfl_up(ws, o, 16);
                if (lane >= o) ws += u;
            }
            wsum[lane] = ws;
        }
        __syncthreads();
        int wpre = (wv > 0) ? wsum[wv - 1] : 0;
        int incl = carry + wpre + s;
        if (i < N_NODES) offs[i + 1] = incl;
        __syncthreads();
        if (t == 1023) carry = incl;
        __syncthreads();
    }
}

__global__ __launch_bounds__(256) void scatter_kernel(const int* __restrict__ ei,
                                                      int* __restrict__ offs,
                                                      int* __restrict__ eids) {
    int e = blockIdx.x * 256 + threadIdx.x;
    if (e < E_EDGES) {
        int d = ei[E_EDGES + e];
        int p = atomicAdd(&offs[d], 1);
        eids[p] = e;
    }
}

// position maps: pos_of[e] = p; posrev[p] = pos_of[rev[eids[p]]]
__global__ __launch_bounds__(256) void posA_kernel(const int* __restrict__ eids,
                                                   int* __restrict__ pos_of) {
    int p = blockIdx.x * 256 + threadIdx.x;
    if (p < E_EDGES) pos_of[eids[p]] = p;
}
__global__ __launch_bounds__(256) void posB_kernel(const int* __restrict__ eids,
                                                   const int* __restrict__ rev,
                                                   const int* __restrict__ pos_of,
                                                   int* __restrict__ posrev) {
    int p = blockIdx.x * 256 + threadIdx.x;
    if (p < E_EDGES) posrev[p] = pos_of[rev[eids[p]]];
}

// ---------------- segment sum via CSR (B path) ----------------
__global__ __launch_bounds__(256) void segsum_kernel(const short* __restrict__ H,
                                                     const int* __restrict__ eids,
                                                     const int* __restrict__ offs,
                                                     float* __restrict__ agg,
                                                     float* __restrict__ flg) {
    const int w = threadIdx.x >> 6, l = threadIdx.x & 63;
    const int n = blockIdx.x * 4 + w;
    if (n >= N_NODES) return;
    int b = (n == 0) ? 0 : offs[n - 1];
    int en = offs[n];
    float s0 = 0.f, s1 = 0.f, t0 = 0.f, t1 = 0.f;
    int j = b;
    for (; j + 2 <= en; j += 2) {
        int e0 = eids[j], e1 = eids[j + 1];
        unsigned int pk0 = *(const unsigned int*)(H + (size_t)e0 * 128 + l * 2);
        unsigned int pk1 = *(const unsigned int*)(H + (size_t)e1 * 128 + l * 2);
        s0 += bf2f((u16)(pk0 & 0xffffu));
        s1 += bf2f((u16)(pk0 >> 16));
        t0 += bf2f((u16)(pk1 & 0xffffu));
        t1 += bf2f((u16)(pk1 >> 16));
    }
    if (j < en) {
        int e0 = eids[j];
        unsigned int pk0 = *(const unsigned int*)(H + (size_t)e0 * 128 + l * 2);
        s0 += bf2f((u16)(pk0 & 0xffffu));
        s1 += bf2f((u16)(pk0 >> 16));
    }
    s0 += t0; s1 += t1;
    agg[(size_t)n * 128 + l * 2] = s0;
    agg[(size_t)n * 128 + l * 2 + 1] = s1;
    if (flg) {
        float s = s0 + s1;
#pragma unroll
        for (int off = 32; off; off >>= 1) s += __shfl_xor(s, off, 64);
        if (l == 0) flg[n] = s;
    }
}

__global__ __launch_bounds__(256) void flag_kernel(const float* __restrict__ agg,
                                                   float* __restrict__ flg) {
    const int w = threadIdx.x >> 6, l = threadIdx.x & 63;
    const int n = blockIdx.x * 4 + w;
    if (n >= N_NODES) return;
    const float* r = agg + (size_t)n * 128 + l * 2;
    float s = r[0] + r[1];
#pragma unroll
    for (int off = 32; off; off >>= 1) s += __shfl_xor(s, off, 64);
    if (l == 0) flg[n] = s;
}

// ---------------- A: dst-ordered H0 (position-ordered store) + fused segreduce -> agg1 ----------------
__global__ __launch_bounds__(256) void h0dst_kernel(
    const short* __restrict__ xb, const short* __restrict__ eb,
    const short* __restrict__ WiT, const float* __restrict__ bi,
    const int* __restrict__ ei, const int* __restrict__ eids,
    const int* __restrict__ offs, short* __restrict__ H0,
    float* __restrict__ agg1) {
    __shared__ short Bx[128 * 128];  // x-part of Wi, XOR-swizzled
    __shared__ short T[64 * 128];    // swizzled output tile
    __shared__ int eloc[64], dstv[64];
    const int P = xcd_swz(blockIdx.x, gridDim.x) * 64;
    for (int i = threadIdx.x; i < 128 * 16; i += 256) {
        int row = i >> 4, cc = i & 15;
        int dstByte = row * 256 + ((cc * 16) ^ ((row & 7) << 4));
        *(bf16x8*)((char*)Bx + dstByte) = *(const bf16x8*)&WiT[row * 160 + cc * 8];
    }
    if (threadIdx.x < 64) {
        int e = eids[P + threadIdx.x];
        eloc[threadIdx.x] = e;
        dstv[threadIdx.x] = ei[E_EDGES + e];
    }
    __syncthreads();
    const int w = threadIdx.x >> 6, l = threadIdx.x & 63;
    const int c = l & 15, g = l >> 4;
    const int em = eloc[w * 16 + c];
    const int src_e = ei[em];
    const short* xr = xb + (size_t)src_e * 128;
    const short* ar = eb + (size_t)em * 16;

    bf16x8 px[4];
#pragma unroll
    for (int s = 0; s < 4; ++s) px[s] = *(const bf16x8*)(xr + s * 32 + g * 8);
    bf16x8 pe = {0, 0, 0, 0, 0, 0, 0, 0};
    if (g < 2) pe = *(const bf16x8*)(ar + g * 8);
    const int weOff = 128 + (g & 1) * 8;

    f32x4 acc[8] = {};
#pragma unroll
    for (int s = 0; s < 5; ++s) {
        const int k0 = s * 32 + g * 8;
        bf16x8 af = (s < 4) ? px[s] : pe;
#pragma unroll
        for (int nf = 0; nf < 8; ++nf) {
            const int row = nf * 16 + c;
            bf16x8 bfv;
            if (s < 4) {
                int bo = row * 256 + ((k0 * 2) ^ ((row & 7) << 4));
                bfv = *(const bf16x8*)((char*)Bx + bo);
            } else {
                bfv = *(const bf16x8*)&WiT[row * 160 + weOff];
            }
            acc[nf] = __builtin_amdgcn_mfma_f32_16x16x32_bf16(af, bfv, acc[nf], 0, 0, 0);
        }
    }
#pragma unroll
    for (int nf = 0; nf < 8; ++nf) {
        const int col = nf * 16 + c;
        const float bias = bi[col];
#pragma unroll
        for (int r = 0; r < 4; ++r) {
            const int lr2 = w * 16 + g * 4 + r;
            float v = fmaxf(acc[nf][r] + bias, 0.0f);
            int bo = lr2 * 256 + ((col * 2) ^ ((lr2 & 7) << 4));
            *(short*)((char*)T + bo) = (short)f2bf(v);
        }
    }
    __syncthreads();
    // contiguous position-ordered H0 store
#pragma unroll
    for (int it = 0; it < 4; ++it) {
        int i = threadIdx.x + it * 256;
        int lr = i >> 4, cc = i & 15;
        int bo = lr * 256 + ((cc * 16) ^ ((lr & 7) << 4));
        *(bf16x8*)&H0[(size_t)(P + lr) * 128 + cc * 8] = *(const bf16x8*)((char*)T + bo);
    }
    // segmented reduce T -> agg1 (2 halves x 32 rows)
    {
        const int h = threadIdx.x >> 7;
        const int col = threadIdx.x & 127;
        const int base = h * 32;
        const int Ph = P + base;
        int n0 = dstv[base];
        bool fh0 = (((n0 == 0) ? 0 : offs[n0 - 1]) == Ph);
        bool fh1 = (offs[dstv[base + 31]] == Ph + 32);
        float sum = 0.f;
        int cur = n0, segStart = base;
        for (int lr = base; lr < base + 32; ++lr) {
            int d = dstv[lr];
            int bo = lr * 256 + ((col * 2) ^ ((lr & 7) << 4));
            float v = bf2f(*(const u16*)((char*)T + bo));
            if (d != cur) {
                bool comp = (segStart > base) || fh0;
                float* dp = agg1 + (size_t)cur * 128 + col;
                if (comp) *dp = sum; else atomicAdd(dp, sum);
                cur = d; segStart = lr; sum = v;
            } else {
                sum += v;
            }
        }
        bool comp = ((segStart > base) || fh0) && fh1;
        float* dp = agg1 + (size_t)cur * 128 + col;
        if (comp) *dp = sum; else atomicAdd(dp, sum);
    }
}

// ---------------- A: dst-ordered iteration (position-ordered H0) ----------------
__global__ __launch_bounds__(256) void iter_dst_kernel(
    const float* __restrict__ agg1, const short* __restrict__ H0,
    const short* __restrict__ WhT, const float* __restrict__ bh,
    const int* __restrict__ ei, const int* __restrict__ posrev,
    const int* __restrict__ eids, const int* __restrict__ offs,
    float* __restrict__ agg2) {
    __shared__ short B[128 * 136];
    __shared__ short T[64 * 136];
    __shared__ int eloc[64], dstv[64];
    const int P = xcd_swz(blockIdx.x, gridDim.x) * 64;
    for (int i = threadIdx.x; i < 128 * 16; i += 256) {
        int row = i >> 4, cc = i & 15;
        *(bf16x8*)&B[row * 136 + cc * 8] = *(const bf16x8*)&WhT[row * 128 + cc * 8];
    }
    if (threadIdx.x < 64) {
        int e = eids[P + threadIdx.x];
        eloc[threadIdx.x] = e;
        dstv[threadIdx.x] = ei[E_EDGES + e];
    }
    __syncthreads();
    const int w = threadIdx.x >> 6, l = threadIdx.x & 63;
    const int c = l & 15, g = l >> 4;
    const int src_e = ei[eloc[w * 16 + c]];
    const int prv = posrev[P + w * 16 + c];
    const float* arow = agg1 + (size_t)src_e * 128;
    const short* hrow = H0 + (size_t)prv * 128;

    bf16x8 stg[4];
#pragma unroll
    for (int it = 0; it < 4; ++it) {
        int i = threadIdx.x + it * 256;
        int lr = i >> 4, cc = i & 15;
        stg[it] = *(const bf16x8*)&H0[(size_t)(P + lr) * 128 + cc * 8];
    }
    f32x4 pa[4][2];
    bf16x8 ph[4];
#pragma unroll
    for (int s = 0; s < 4; ++s) {
        pa[s][0] = *(const f32x4*)(arow + s * 32 + g * 8);
        pa[s][1] = *(const f32x4*)(arow + s * 32 + g * 8 + 4);
        ph[s] = *(const bf16x8*)(hrow + s * 32 + g * 8);
    }
#pragma unroll
    for (int it = 0; it < 4; ++it) {
        int i = threadIdx.x + it * 256;
        int lr = i >> 4, cc = i & 15;
        *(bf16x8*)&T[lr * 136 + cc * 8] = stg[it];
    }
    __syncthreads();

    f32x4 acc[8] = {};
#pragma unroll
    for (int s = 0; s < 4; ++s) {
        const int k0 = s * 32 + g * 8;
        bf16x8 af;
#pragma unroll
        for (int j = 0; j < 8; ++j) {
            float aj = ((j < 4) ? pa[s][0][j] : pa[s][1][j - 4]) - bf2f((u16)ph[s][j]);
            af[j] = (short)f2bf(aj);
        }
#pragma unroll
        for (int nf = 0; nf < 8; ++nf) {
            bf16x8 bfv = *(const bf16x8*)&B[(nf * 16 + c) * 136 + k0];
            acc[nf] = __builtin_amdgcn_mfma_f32_16x16x32_bf16(af, bfv, acc[nf], 0, 0, 0);
        }
    }
#pragma unroll
    for (int nf = 0; nf < 8; ++nf) {
        const int col = nf * 16 + c;
        const float bias = bh[col];
#pragma unroll
        for (int r = 0; r < 4; ++r) {
            const int lr2 = w * 16 + g * 4 + r;
            float res = bf2f((u16)T[lr2 * 136 + col]);
            float v = fmaxf(acc[nf][r] + bias + res, 0.0f);
            T[lr2 * 136 + col] = (short)f2bf(v);
        }
    }
    __syncthreads();
    {
        const int h = threadIdx.x >> 7;
        const int col = threadIdx.x & 127;
        const int base = h * 32;
        const int Ph = P + base;
        int n0 = dstv[base];
        bool fh0 = (((n0 == 0) ? 0 : offs[n0 - 1]) == Ph);
        bool fh1 = (offs[dstv[base + 31]] == Ph + 32);
        float sum = 0.f;
        int cur = n0, segStart = base;
        for (int lr = base; lr < base + 32; ++lr) {
            int d = dstv[lr];
            float v = bf2f((u16)T[lr * 136 + col]);
            if (d != cur) {
                bool comp = (segStart > base) || fh0;
                float* dp = agg2 + (size_t)cur * 128 + col;
                if (comp) *dp = sum; else atomicAdd(dp, sum);
                cur = d; segStart = lr; sum = v;
            } else {
                sum += v;
            }
        }
        bool comp = ((segStart > base) || fh0) && fh1;
        float* dp = agg2 + (size_t)cur * 128 + col;
        if (comp) *dp = sum; else atomicAdd(dp, sum);
    }
}

// ---------------- A: fused final iteration (position-ordered H0, late residual) ----------------
__global__ __launch_bounds__(256) void iter2F_kernel(
    const float* __restrict__ agg1, const float* __restrict__ agg2,
    const short* __restrict__ H0, const short* __restrict__ WhT,
    const float* __restrict__ bh, const int* __restrict__ ei,
    const int* __restrict__ posrev, const int* __restrict__ eids,
    const int* __restrict__ offs, float* __restrict__ aggF) {
    __shared__ short B[128 * 128];   // Wh, XOR-swizzled
    __shared__ short TR[64 * 128];   // swizzled: H0[rev] -> H1[rev] -> H2
    __shared__ int eloc[64], dstv[64], prl[64];
    const int P = xcd_swz(blockIdx.x, gridDim.x) * 64;
    for (int i = threadIdx.x; i < 128 * 16; i += 256) {
        int row = i >> 4, cc = i & 15;
        int dstByte = row * 256 + ((cc * 16) ^ ((row & 7) << 4));
        *(bf16x8*)((char*)B + dstByte) = *(const bf16x8*)&WhT[row * 128 + cc * 8];
    }
    if (threadIdx.x < 64) {
        int e = eids[P + threadIdx.x];
        eloc[threadIdx.x] = e;
        dstv[threadIdx.x] = ei[E_EDGES + e];
        prl[threadIdx.x] = posrev[P + threadIdx.x];
    }
    __syncthreads();
#pragma unroll
    for (int it = 0; it < 4; ++it) {
        int i = threadIdx.x + it * 256;
        int lr = i >> 4, cc = i & 15;
        int bo = lr * 256 + ((cc * 16) ^ ((lr & 7) << 4));
        *(bf16x8*)((char*)TR + bo) = *(const bf16x8*)&H0[(size_t)prl[lr] * 128 + cc * 8];
    }
    const int w = threadIdx.x >> 6, l = threadIdx.x & 63;
    const int c = l & 15, g = l >> 4;
    const int rl = w * 16 + c;
    const int em = eloc[rl];
    const int dst_em = dstv[rl];
    const int src_m = ei[em];
    const short* h0row = H0 + (size_t)(P + rl) * 128;
    const float* a1row = agg1 + (size_t)dst_em * 128;
    const float* a2row = agg2 + (size_t)src_m * 128;

    bf16x8 ph[4];
    f32x4 pa1[4][2], pa2[4][2];
#pragma unroll
    for (int s = 0; s < 4; ++s) {
        ph[s] = *(const bf16x8*)(h0row + s * 32 + g * 8);
        pa1[s][0] = *(const f32x4*)(a1row + s * 32 + g * 8);
        pa1[s][1] = *(const f32x4*)(a1row + s * 32 + g * 8 + 4);
        pa2[s][0] = *(const f32x4*)(a2row + s * 32 + g * 8);
        pa2[s][1] = *(const f32x4*)(a2row + s * 32 + g * 8 + 4);
    }
    __syncthreads();

    // phase 1: H1[rev_em] = relu(H0[rev_em] + (agg1[dst_em] - H0[em]) @ Wh + bh)
    f32x4 acc[8] = {};
#pragma unroll
    for (int s = 0; s < 4; ++s) {
        const int k0 = s * 32 + g * 8;
        bf16x8 af;
#pragma unroll
        for (int j = 0; j < 8; ++j) {
            float aj = ((j < 4) ? pa1[s][0][j] : pa1[s][1][j - 4]) - bf2f((u16)ph[s][j]);
            af[j] = (short)f2bf(aj);
        }
#pragma unroll
        for (int nf = 0; nf < 8; ++nf) {
            const int row = nf * 16 + c;
            int bo = row * 256 + ((k0 * 2) ^ ((row & 7) << 4));
            bf16x8 bfv = *(const bf16x8*)((char*)B + bo);
            acc[nf] = __builtin_amdgcn_mfma_f32_16x16x32_bf16(af, bfv, acc[nf], 0, 0, 0);
        }
    }
#pragma unroll
    for (int nf = 0; nf < 8; ++nf) {
        const int col = nf * 16 + c;
        const float bias = bh[col];
#pragma unroll
        for (int r = 0; r < 4; ++r) {
            const int lr2 = w * 16 + g * 4 + r;
            int bo = lr2 * 256 + ((col * 2) ^ ((lr2 & 7) << 4));
            float res = bf2f(*(const u16*)((char*)TR + bo));
            float v = fmaxf(acc[nf][r] + bias + res, 0.0f);
            *(short*)((char*)TR + bo) = (short)f2bf(v);
        }
    }
    __syncthreads();
    // phase 2: H2[em] = relu(H0[em] + (agg2[src_em] - H1[rev_em]) @ Wh + bh)
    f32x4 acc2[8] = {};
#pragma unroll
    for (int s = 0; s < 4; ++s) {
        const int k0 = s * 32 + g * 8;
        int boT = rl * 256 + ((k0 * 2) ^ ((rl & 7) << 4));
        bf16x8 hv = *(const bf16x8*)((char*)TR + boT);
        bf16x8 af;
#pragma unroll
        for (int j = 0; j < 8; ++j) {
            float aj = ((j < 4) ? pa2[s][0][j] : pa2[s][1][j - 4]) - bf2f((u16)hv[j]);
            af[j] = (short)f2bf(aj);
        }
#pragma unroll
        for (int nf = 0; nf < 8; ++nf) {
            const int row = nf * 16 + c;
            int bo = row * 256 + ((k0 * 2) ^ ((row & 7) << 4));
            bf16x8 bfv = *(const bf16x8*)((char*)B + bo);
            acc2[nf] = __builtin_amdgcn_mfma_f32_16x16x32_bf16(af, bfv, acc2[nf], 0, 0, 0);
        }
    }
    __syncthreads();  // all H1 reads complete before overwriting TR with H2
    // late residual: block's own contiguous rows -> L1-hot
#pragma unroll
    for (int nf = 0; nf < 8; ++nf) {
        const int col = nf * 16 + c;
        const float bias = bh[col];
#pragma unroll
        for (int r = 0; r < 4; ++r) {
            const int lr2 = w * 16 + g * 4 + r;
            float res = bf2f((u16)H0[(size_t)(P + lr2) * 128 + col]);
            float v = fmaxf(acc2[nf][r] + bias + res, 0.0f);
            int bo = lr2 * 256 + ((col * 2) ^ ((lr2 & 7) << 4));
            *(short*)((char*)TR + bo) = (short)f2bf(v);
        }
    }
    __syncthreads();
    {
        const int h = threadIdx.x >> 7;
        const int col = threadIdx.x & 127;
        const int base = h * 32;
        const int Ph = P + base;
        int n0 = dstv[base];
        bool fh0 = (((n0 == 0) ? 0 : offs[n0 - 1]) == Ph);
        bool fh1 = (offs[dstv[base + 31]] == Ph + 32);
        float sum = 0.f;
        int cur = n0, segStart = base;
        for (int lr = base; lr < base + 32; ++lr) {
            int d = dstv[lr];
            int bo = lr * 256 + ((col * 2) ^ ((lr & 7) << 4));
            float v = bf2f(*(const u16*)((char*)TR + bo));
            if (d != cur) {
                bool comp = (segStart > base) || fh0;
                float* dp = aggF + (size_t)cur * 128 + col;
                if (comp) *dp = sum; else atomicAdd(dp, sum);
                cur = d; segStart = lr; sum = v;
            } else {
                sum += v;
            }
        }
        bool comp = ((segStart > base) || fh0) && fh1;
        float* dp = aggF + (size_t)cur * 128 + col;
        if (comp) *dp = sum; else atomicAdd(dp, sum);
    }
}

// ---------------- B-path kernels (unchanged) ----------------
__global__ __launch_bounds__(256) void h0s_kernel(
    const float* __restrict__ x, const float* __restrict__ eattr,
    const short* __restrict__ WiT, const float* __restrict__ bi,
    const int* __restrict__ ei, short* __restrict__ H0) {
    __shared__ short B[128 * 168];
    for (int i = threadIdx.x; i < 128 * 20; i += 256) {
        int row = i / 20, cc = i % 20;
        *(bf16x8*)&B[row * 168 + cc * 8] = *(const bf16x8*)&WiT[row * 160 + cc * 8];
    }
    __syncthreads();
    const int w = threadIdx.x >> 6, l = threadIdx.x & 63;
    const int c = l & 15, g = l >> 4;
    const int e0 = blockIdx.x * 64 + w * 16;
    const int em = e0 + c;
    const int src_e = ei[em];
    const float* xr = x + (size_t)src_e * 128;
    const float* ar = eattr + (size_t)em * 16;

    f32x4 acc[8] = {};
#pragma unroll
    for (int s = 0; s < 5; ++s) {
        const int k0 = s * 32 + g * 8;
        float av[8];
        if (s < 4) {
            f32x4 p0 = *(const f32x4*)(xr + k0);
            f32x4 p1 = *(const f32x4*)(xr + k0 + 4);
#pragma unroll
            for (int j = 0; j < 4; ++j) { av[j] = p0[j]; av[j + 4] = p1[j]; }
        } else {
            if (g < 2) {
                f32x4 p0 = *(const f32x4*)(ar + g * 8);
                f32x4 p1 = *(const f32x4*)(ar + g * 8 + 4);
#pragma unroll
                for (int j = 0; j < 4; ++j) { av[j] = p0[j]; av[j + 4] = p1[j]; }
            } else {
#pragma unroll
                for (int j = 0; j < 8; ++j) av[j] = 0.f;
            }
        }
        bf16x8 af;
#pragma unroll
        for (int j = 0; j < 8; ++j) af[j] = (short)f2bf(av[j]);
#pragma unroll
        for (int nf = 0; nf < 8; ++nf) {
            bf16x8 bfv = *(const bf16x8*)&B[(nf * 16 + c) * 168 + k0];
            acc[nf] = __builtin_amdgcn_mfma_f32_16x16x32_bf16(af, bfv, acc[nf], 0, 0, 0);
        }
    }
#pragma unroll
    for (int nf = 0; nf < 8; ++nf) {
        const int col = nf * 16 + c;
        const float bias = bi[col];
#pragma unroll
        for (int r = 0; r < 4; ++r) {
            const int er = e0 + g * 4 + r;
            float v = fmaxf(acc[nf][r] + bias, 0.0f);
            H0[(size_t)er * 128 + col] = (short)f2bf(v);
        }
    }
}

__global__ __launch_bounds__(256) void iterx_kernel(
    const float* __restrict__ agg, const short* __restrict__ Hrev,
    const short* Hres, const short* __restrict__ WhT,
    const float* __restrict__ bh, const int* __restrict__ ei,
    const int* __restrict__ rev, short* Hout) {
    __shared__ short B[128 * 136];
    for (int i = threadIdx.x; i < 128 * 16; i += 256) {
        int row = i >> 4, cc = i & 15;
        *(bf16x8*)&B[row * 136 + cc * 8] = *(const bf16x8*)&WhT[row * 128 + cc * 8];
    }
    __syncthreads();
    const int w = threadIdx.x >> 6, l = threadIdx.x & 63;
    const int c = l & 15, g = l >> 4;
    const int e0 = blockIdx.x * 64 + w * 16;
    const int em = e0 + c;
    const int src_e = ei[em];
    const int rev_e = rev[em];
    const float* arow = agg + (size_t)src_e * 128;
    const short* hrow = Hrev + (size_t)rev_e * 128;

    f32x4 acc[8] = {};
#pragma unroll
    for (int s = 0; s < 4; ++s) {
        const int k0 = s * 32 + g * 8;
        f32x4 p0 = *(const f32x4*)(arow + k0);
        f32x4 p1 = *(const f32x4*)(arow + k0 + 4);
        bf16x8 hv = *(const bf16x8*)(hrow + k0);
        bf16x8 af;
#pragma unroll
        for (int j = 0; j < 8; ++j) {
            float aj = ((j < 4) ? p0[j] : p1[j - 4]) - bf2f((u16)hv[j]);
            af[j] = (short)f2bf(aj);
        }
#pragma unroll
        for (int nf = 0; nf < 8; ++nf) {
            bf16x8 bfv = *(const bf16x8*)&B[(nf * 16 + c) * 136 + k0];
            acc[nf] = __builtin_amdgcn_mfma_f32_16x16x32_bf16(af, bfv, acc[nf], 0, 0, 0);
        }
    }
#pragma unroll
    for (int nf = 0; nf < 8; ++nf) {
        const int col = nf * 16 + c;
        const float bias = bh[col];
#pragma unroll
        for (int r = 0; r < 4; ++r) {
            const int er = e0 + g * 4 + r;
            float v = acc[nf][r] + bias + bf2f((u16)Hres[(size_t)er * 128 + col]);
            v = fmaxf(v, 0.0f);
            Hout[(size_t)er * 128 + col] = (short)f2bf(v);
        }
    }
}

// ---------------- LOW-fallback kernels ----------------
__global__ __launch_bounds__(256) void h0_kernel(
    const float* __restrict__ x, const float* __restrict__ eattr,
    const short* __restrict__ WiT, const float* __restrict__ bi,
    const int* __restrict__ ei, short* __restrict__ H0, float* __restrict__ agg) {
    __shared__ short B[128 * 168];
    for (int i = threadIdx.x; i < 128 * 20; i += 256) {
        int row = i / 20, cc = i % 20;
        *(bf16x8*)&B[row * 168 + cc * 8] = *(const bf16x8*)&WiT[row * 160 + cc * 8];
    }
    __syncthreads();
    const int w = threadIdx.x >> 6, l = threadIdx.x & 63;
    const int c = l & 15, g = l >> 4;
    const int e0 = blockIdx.x * 64 + w * 16;
    const int em = e0 + c;
    const int src_e = ei[em];
    const float* xr = x + (size_t)src_e * 128;
    const float* ar = eattr + (size_t)em * 16;
    f32x4 acc[8] = {};
#pragma unroll
    for (int s = 0; s < 5; ++s) {
        const int k0 = s * 32 + g * 8;
        float av[8];
        if (s < 4) {
            f32x4 p0 = *(const f32x4*)(xr + k0);
            f32x4 p1 = *(const f32x4*)(xr + k0 + 4);
#pragma unroll
            for (int j = 0; j < 4; ++j) { av[j] = p0[j]; av[j + 4] = p1[j]; }
        } else {
            if (g < 2) {
                f32x4 p0 = *(const f32x4*)(ar + g * 8);
                f32x4 p1 = *(const f32x4*)(ar + g * 8 + 4);
#pragma unroll
                for (int j = 0; j < 4; ++j) { av[j] = p0[j]; av[j + 4] = p1[j]; }
            } else {
#pragma unroll
                for (int j = 0; j < 8; ++j) av[j] = 0.f;
            }
        }
        bf16x8 af;
#pragma unroll
        for (int j = 0; j < 8; ++j) af[j] = (short)f2bf(av[j]);
#pragma unroll
        for (int nf = 0; nf < 8; ++nf) {
            bf16x8 bfv = *(const bf16x8*)&B[(nf * 16 + c) * 168 + k0];
            acc[nf] = __builtin_amdgcn_mfma_f32_16x16x32_bf16(af, bfv, acc[nf], 0, 0, 0);
        }
    }
    int dsts[4];
#pragma unroll
    for (int r = 0; r < 4; ++r) dsts[r] = ei[E_EDGES + e0 + g * 4 + r];
#pragma unroll
    for (int nf = 0; nf < 8; ++nf) {
        const int col = nf * 16 + c;
        const float bias = bi[col];
#pragma unroll
        for (int r = 0; r < 4; ++r) {
            const int er = e0 + g * 4 + r;
            float v = fmaxf(acc[nf][r] + bias, 0.0f);
            u16 hb = f2bf(v);
            H0[(size_t)er * 128 + col] = (short)hb;
            atomicAdd(agg + (size_t)dsts[r] * 128 + col, bf2f(hb));
        }
    }
}

__global__ __launch_bounds__(256) void iter_atomic_kernel(
    const float* __restrict__ aggin, const short* __restrict__ Hin,
    const short* __restrict__ H0, const short* __restrict__ WhT,
    const float* __restrict__ bh, const int* __restrict__ ei,
    const int* __restrict__ rev, float* __restrict__ aggout) {
    __shared__ short B[128 * 136];
    for (int i = threadIdx.x; i < 128 * 16; i += 256) {
        int row = i >> 4, cc = i & 15;
        *(bf16x8*)&B[row * 136 + cc * 8] = *(const bf16x8*)&WhT[row * 128 + cc * 8];
    }
    __syncthreads();
    const int w = threadIdx.x >> 6, l = threadIdx.x & 63;
    const int c = l & 15, g = l >> 4;
    const int e0 = blockIdx.x * 64 + w * 16;
    const int em = e0 + c;
    const int src_e = ei[em];
    const int rev_e = rev[em];
    const float* arow = aggin + (size_t)src_e * 128;
    const short* hrow = Hin + (size_t)rev_e * 128;

    f32x4 acc[8] = {};
#pragma unroll
    for (int s = 0; s < 4; ++s) {
        const int k0 = s * 32 + g * 8;
        f32x4 p0 = *(const f32x4*)(arow + k0);
        f32x4 p1 = *(const f32x4*)(arow + k0 + 4);
        bf16x8 hv = *(const bf16x8*)(hrow + k0);
        bf16x8 af;
#pragma unroll
        for (int j = 0; j < 8; ++j) {
            float aj = ((j < 4) ? p0[j] : p1[j - 4]) - bf2f((u16)hv[j]);
            af[j] = (short)f2bf(aj);
        }
#pragma unroll
        for (int nf = 0; nf < 8; ++nf) {
            bf16x8 bfv = *(const bf16x8*)&B[(nf * 16 + c) * 136 + k0];
            acc[nf] = __builtin_amdgcn_mfma_f32_16x16x32_bf16(af, bfv, acc[nf], 0, 0, 0);
        }
    }
    int dsts[4];
#pragma unroll
    for (int r = 0; r < 4; ++r) dsts[r] = ei[E_EDGES + e0 + g * 4 + r];
#pragma unroll
    for (int nf = 0; nf < 8; ++nf) {
        const int col = nf * 16 + c;
        const float bias = bh[col];
#pragma unroll
        for (int r = 0; r < 4; ++r) {
            const int er = e0 + g * 4 + r;
            float v = acc[nf][r] + bias + bf2f((u16)H0[(size_t)er * 128 + col]);
            v = fmaxf(v, 0.0f);
            atomicAdd(aggout + (size_t)dsts[r] * 128 + col, bf2f(f2bf(v)));
        }
    }
}

__global__ __launch_bounds__(256) void iter2c_kernel(
    const float* __restrict__ agg1, const float* __restrict__ agg2,
    const short* __restrict__ H0, const short* __restrict__ WhT,
    const float* __restrict__ bh, const int* __restrict__ ei,
    const int* __restrict__ rev, float* __restrict__ aggF) {
    __shared__ short B[128 * 136];
    __shared__ short T[4][16 * 136];
    for (int i = threadIdx.x; i < 128 * 16; i += 256) {
        int row = i >> 4, cc = i & 15;
        *(bf16x8*)&B[row * 136 + cc * 8] = *(const bf16x8*)&WhT[row * 128 + cc * 8];
    }
    __syncthreads();
    const int w = threadIdx.x >> 6, l = threadIdx.x & 63;
    const int c = l & 15, g = l >> 4;
    const int e0 = blockIdx.x * 64 + w * 16;
    const int em = e0 + c;
    const int dst_em = ei[E_EDGES + em];
    const int src_em = ei[em];
    const float* a1row = agg1 + (size_t)dst_em * 128;
    const float* a2row = agg2 + (size_t)src_em * 128;
    const short* h0row = H0 + (size_t)em * 128;
    int rows[4], revs[4], dsts[4];
#pragma unroll
    for (int r = 0; r < 4; ++r) {
        rows[r] = e0 + g * 4 + r;
        revs[r] = rev[rows[r]];
        dsts[r] = ei[E_EDGES + rows[r]];
    }
    f32x4 acc[8] = {};
#pragma unroll
    for (int s = 0; s < 4; ++s) {
        const int k0 = s * 32 + g * 8;
        f32x4 p0 = *(const f32x4*)(a1row + k0);
        f32x4 p1 = *(const f32x4*)(a1row + k0 + 4);
        bf16x8 hv = *(const bf16x8*)(h0row + k0);
        bf16x8 af;
#pragma unroll
        for (int j = 0; j < 8; ++j) {
            float aj = ((j < 4) ? p0[j] : p1[j - 4]) - bf2f((u16)hv[j]);
            af[j] = (short)f2bf(aj);
        }
#pragma unroll
        for (int nf = 0; nf < 8; ++nf) {
            bf16x8 bfv = *(const bf16x8*)&B[(nf * 16 + c) * 136 + k0];
            acc[nf] = __builtin_amdgcn_mfma_f32_16x16x32_bf16(af, bfv, acc[nf], 0, 0, 0);
        }
    }
#pragma unroll
    for (int nf = 0; nf < 8; ++nf) {
        const int col = nf * 16 + c;
        const float bias = bh[col];
#pragma unroll
        for (int r = 0; r < 4; ++r) {
            float res = bf2f((u16)H0[(size_t)revs[r] * 128 + col]);
            float v = fmaxf(acc[nf][r] + bias + res, 0.0f);
            T[w][(g * 4 + r) * 136 + col] = (short)f2bf(v);
        }
    }
    __syncthreads();
    f32x4 acc2[8] = {};
#pragma unroll
    for (int s = 0; s < 4; ++s) {
        const int k0 = s * 32 + g * 8;
        f32x4 p0 = *(const f32x4*)(a2row + k0);
        f32x4 p1 = *(const f32x4*)(a2row + k0 + 4);
        bf16x8 hv = *(const bf16x8*)&T[w][c * 136 + k0];
        bf16x8 af;
#pragma unroll
        for (int j = 0; j < 8; ++j) {
            float aj = ((j < 4) ? p0[j] : p1[j - 4]) - bf2f((u16)hv[j]);
            af[j] = (short)f2bf(aj);
        }
#pragma unroll
        for (int nf = 0; nf < 8; ++nf) {
            bf16x8 bfv = *(const bf16x8*)&B[(nf * 16 + c) * 136 + k0];
            acc2[nf] = __builtin_amdgcn_mfma_f32_16x16x32_bf16(af, bfv, acc2[nf], 0, 0, 0);
        }
    }
#pragma unroll
    for (int nf = 0; nf < 8; ++nf) {
        const int col = nf * 16 + c;
        const float bias = bh[col];
#pragma unroll
        for (int r = 0; r < 4; ++r) {
            float res = bf2f((u16)H0[(size_t)rows[r] * 128 + col]);
            float v = fmaxf(acc2[nf][r] + bias + res, 0.0f);
            atomicAdd(aggF + (size_t)dsts[r] * 128 + col, v);
        }
    }
}

// ---------------- output ----------------
__global__ __launch_bounds__(256) void out_kernel(
    const float* __restrict__ x, const float* agg,
    const float* __restrict__ flg, const short* __restrict__ WoT,
    const float* __restrict__ bo, float* out) {
    __shared__ short B[128 * 256];
    for (int i = threadIdx.x; i < 128 * 32; i += 256) {
        int row = i >> 5, cc = i & 31;
        int dstByte = row * 512 + ((cc * 16) ^ ((row & 7) << 4));
        *(bf16x8*)((char*)B + dstByte) = *(const bf16x8*)&WoT[row * 256 + cc * 8];
    }
    __syncthreads();
    const int w = threadIdx.x >> 6, l = threadIdx.x & 63;
    const int c = l & 15, g = l >> 4;
    const int n0 = blockIdx.x * 64 + w * 16;
    const int nm = n0 + c;
    const int nmc = nm < N_NODES ? nm : N_NODES - 1;
    const float* xr = x + (size_t)nmc * 128;
    const float* mr = agg + (size_t)nmc * 128;
    const bool usex = (flg[nmc] == 0.0f);
    f32x4 acc[8] = {};
#pragma unroll
    for (int s = 0; s < 8; ++s) {
        const int k0 = s * 32 + g * 8;
        const float* srcp;
        int kk;
        if (s < 4) { srcp = xr; kk = k0; }
        else       { srcp = usex ? xr : mr; kk = k0 - 128; }
        f32x4 p0 = *(const f32x4*)(srcp + kk);
        f32x4 p1 = *(const f32x4*)(srcp + kk + 4);
        bf16x8 af;
#pragma unroll
        for (int j = 0; j < 4; ++j) {
            af[j] = (short)f2bf(p0[j]);
            af[j + 4] = (short)f2bf(p1[j]);
        }
#pragma unroll
        for (int nf = 0; nf < 8; ++nf) {
            int row = nf * 16 + c;
            int byteOff = row * 512 + ((k0 * 2) ^ ((row & 7) << 4));
            bf16x8 bfv = *(const bf16x8*)((char*)B + byteOff);
            acc[nf] = __builtin_amdgcn_mfma_f32_16x16x32_bf16(af, bfv, acc[nf], 0, 0, 0);
        }
    }
#pragma unroll
    for (int nf = 0; nf < 8; ++nf) {
        const int col = nf * 16 + c;
        const float bias = bo[col];
#pragma unroll
        for (int r = 0; r < 4; ++r) {
            const int er = n0 + g * 4 + r;
            if (er < N_NODES) {
                float v = fmaxf(acc[nf][r] + bias, 0.0f);
                out[(size_t)er * 128 + col] = v;
            }
        }
    }
}

extern "C" void kernel_launch(void* const* d_in, const int* in_sizes, int n_in,
                              void* d_out, int out_size, void* d_ws, size_t ws_size,
                              hipStream_t stream) {
    const float* x     = (const float*)d_in[0];
    const float* eattr = (const float*)d_in[1];
    const float* Wi    = (const float*)d_in[2];
    const float* bi    = (const float*)d_in[3];
    const float* Wh    = (const float*)d_in[4];
    const float* bh    = (const float*)d_in[5];
    const float* Wo    = (const float*)d_in[6];
    const float* bo    = (const float*)d_in[7];
    const int*   ei    = (const int*)d_in[8];
    const int*   rev   = (const int*)d_in[9];
    float* out = (float*)d_out;
    (void)in_sizes; (void)n_in; (void)out_size;

    char* ws = (char*)d_ws;
    size_t off = 0;
    auto alloc = [&](size_t bytes) {
        void* p = ws + off;
        off = (off + bytes + 255) & ~(size_t)255;
        return p;
    };
    const int AGG4 = N_NODES * 128 / 4;
    const int EG = E_EDGES / 64;           // 9375
    const int EB = (E_EDGES + 255) / 256;  // 2344
    const int NB4 = (N_NODES + 3) / 4;     // 12500
    const int PREPG = (128 * 160 + 128 * 128 + 128 * 256 + 255) / 256;
    const int PREPXG = (N_NODES * 128 / 4 + E_EDGES * 16 / 4 + 255) / 256;

    if (ws_size >= (size_t)337 * 1000 * 1000) {
        // ---- Option B: fully streaming ----
        short* H0  = (short*)alloc((size_t)E_EDGES * 128 * 2);
        short* H1  = (short*)alloc((size_t)E_EDGES * 128 * 2);
        float* agg = (float*)alloc((size_t)N_NODES * 128 * 4);
        float* flg = (float*)alloc((size_t)N_NODES * 4);
        short* WiT = (short*)alloc(128 * 160 * 2);
        short* WhT = (short*)alloc(128 * 128 * 2);
        short* WoT = (short*)alloc(128 * 256 * 2);
        int* deg   = (int*)alloc((size_t)N_NODES * 4);
        int* offs  = (int*)alloc((size_t)(N_NODES + 1) * 4);
        int* eids  = (int*)alloc((size_t)E_EDGES * 4);

        zero_int_kernel<<<(N_NODES + 255) / 256, 256, 0, stream>>>(deg, N_NODES);
        prep_kernel<<<PREPG, 256, 0, stream>>>(Wi, Wh, Wo, WiT, WhT, WoT);
        count_kernel<<<EB, 256, 0, stream>>>(ei, deg);
        scan_kernel<<<1, 1024, 0, stream>>>(deg, offs);
        scatter_kernel<<<EB, 256, 0, stream>>>(ei, offs, eids);
        h0s_kernel<<<EG, 256, 0, stream>>>(x, eattr, WiT, bi, ei, H0);
        segsum_kernel<<<NB4, 256, 0, stream>>>(H0, eids, offs, agg, nullptr);
        iterx_kernel<<<EG, 256, 0, stream>>>(agg, H0, H0, WhT, bh, ei, rev, H1);
        segsum_kernel<<<NB4, 256, 0, stream>>>(H1, eids, offs, agg, nullptr);
        iterx_kernel<<<EG, 256, 0, stream>>>(agg, H1, H0, WhT, bh, ei, rev, H0);
        segsum_kernel<<<NB4, 256, 0, stream>>>(H0, eids, offs, out, flg);
        out_kernel<<<(N_NODES + 63) / 64, 256, 0, stream>>>(x, out, flg, WoT, bo, out);
    } else if (ws_size >= (size_t)210 * 1000 * 1000) {
        // ---- Option A (r12): position-ordered H0 via posrev map ----
        short* H0     = (short*)alloc((size_t)E_EDGES * 128 * 2);
        float* agg1   = (float*)alloc((size_t)N_NODES * 128 * 4);
        float* agg2   = (float*)alloc((size_t)N_NODES * 128 * 4);
        short* WiT    = (short*)alloc(128 * 160 * 2);
        short* WhT    = (short*)alloc(128 * 128 * 2);
        short* WoT    = (short*)alloc(128 * 256 * 2);
        int* offs     = (int*)alloc((size_t)(N_NODES + 1) * 4);
        int* eids     = (int*)alloc((size_t)E_EDGES * 4);
        int* posrev   = (int*)alloc((size_t)E_EDGES * 4);
        // temporaries aliased into dead regions:
        float* flg    = (float*)agg1;                         // live only after iter2F
        int* deg      = (int*)H0;                             // dead before h0dst
        int* pos_of   = (int*)((char*)H0 + 4 * 1024 * 1024);  // dead before h0dst
        short* xbuf   = (short*)agg2;                         // dead until after h0dst
        short* ebuf   = (short*)out;                          // zeroed after h0dst

        zero_int_kernel<<<(N_NODES + 255) / 256, 256, 0, stream>>>(deg, N_NODES);
        zero_kernel<<<(AGG4 + 255) / 256, 256, 0, stream>>>((f32x4*)agg1, AGG4);
        prep_kernel<<<PREPG, 256, 0, stream>>>(Wi, Wh, Wo, WiT, WhT, WoT);
        prepx_kernel<<<PREPXG, 256, 0, stream>>>(x, eattr, xbuf, ebuf);
        count_kernel<<<EB, 256, 0, stream>>>(ei, deg);
        scan_kernel<<<1, 1024, 0, stream>>>(deg, offs);
        scatter_kernel<<<EB, 256, 0, stream>>>(ei, offs, eids);
        posA_kernel<<<EB, 256, 0, stream>>>(eids, pos_of);
        posB_kernel<<<EB, 256, 0, stream>>>(eids, rev, pos_of, posrev);
        h0dst_kernel<<<EG, 256, 0, stream>>>(xbuf, ebuf, WiT, bi, ei, eids, offs, H0, agg1);
        zero_kernel<<<(AGG4 + 255) / 256, 256, 0, stream>>>((f32x4*)agg2, AGG4);
        zero_kernel<<<(AGG4 + 255) / 256, 256, 0, stream>>>((f32x4*)out, AGG4);
        iter_dst_kernel<<<EG, 256, 0, stream>>>(agg1, H0, WhT, bh, ei, posrev, eids, offs, agg2);
        iter2F_kernel<<<EG, 256, 0, stream>>>(agg1, agg2, H0, WhT, bh, ei, posrev, eids, offs, out);
        flag_kernel<<<NB4, 256, 0, stream>>>(out, flg);
        out_kernel<<<(N_NODES + 63) / 64, 256, 0, stream>>>(x, out, flg, WoT, bo, out);
    } else {
        // ---- LOW fallback ----
        short* H0   = (short*)alloc((size_t)E_EDGES * 128 * 2);
        float* agg1 = (float*)alloc((size_t)N_NODES * 128 * 4);
        float* agg2 = (float*)alloc((size_t)N_NODES * 128 * 4);
        float* flg  = (float*)alloc((size_t)N_NODES * 4);
        short* WiT  = (short*)alloc(128 * 160 * 2);
        short* WhT  = (short*)alloc(128 * 128 * 2);
        short* WoT  = (short*)alloc(128 * 256 * 2);
        float* aggF = out;

        zero_kernel<<<(AGG4 + 255) / 256, 256, 0, stream>>>((f32x4*)agg1, AGG4);
        zero_kernel<<<(AGG4 + 255) / 256, 256, 0, stream>>>((f32x4*)agg2, AGG4);
        zero_kernel<<<(AGG4 + 255) / 256, 256, 0, stream>>>((f32x4*)aggF, AGG4);
        prep_kernel<<<PREPG, 256, 0, stream>>>(Wi, Wh, Wo, WiT, WhT, WoT);
        h0_kernel<<<EG, 256, 0, stream>>>(x, eattr, WiT, bi, ei, H0, agg1);
        iter_atomic_kernel<<<EG, 256, 0, stream>>>(agg1, H0, H0, WhT, bh, ei, rev, agg2);
        iter2c_kernel<<<EG, 256, 0, stream>>>(agg1, agg2, H0, WhT, bh, ei, rev, aggF);
        flag_kernel<<<NB4, 256, 0, stream>>>(aggF, flg);
        out_kernel<<<(N_NODES + 63) / 64, 256, 0, stream>>>(x, aggF, flg, WoT, bo, out);
    }
}